// Round 1
// baseline (628.888 us; speedup 1.0000x reference)
//
#include <hip/hip_runtime.h>

typedef unsigned short u16;
typedef __bf16  bfrag  __attribute__((ext_vector_type(8)));   // MFMA A/B operand (4 VGPRs)
typedef float   f32x4  __attribute__((ext_vector_type(4)));   // MFMA C/D operand
typedef u16     u16x8  __attribute__((ext_vector_type(8)));
typedef u16     u16x4  __attribute__((ext_vector_type(4)));

__device__ __forceinline__ float bf2f(u16 u) {
    unsigned v = ((unsigned)u) << 16;
    return __builtin_bit_cast(float, v);
}
__device__ __forceinline__ u16 f2bf(float f) {   // round-to-nearest-even
    unsigned x = __builtin_bit_cast(unsigned, f);
    unsigned r = (x + 0x7fffu + ((x >> 16) & 1u)) >> 16;
    return (u16)r;
}
__device__ __forceinline__ void g2l16(const u16* g, u16* l) {
    // 16B per lane, lands at lds_base + lane*16 (wave-uniform base)
    __builtin_amdgcn_global_load_lds((__attribute__((address_space(1))) void*)g,
                                     (__attribute__((address_space(3))) void*)l, 16, 0, 0);
}
__device__ __forceinline__ float gelu_tanh(float x) {
    float c = 0.7978845608028654f * (x + 0.044715f * x * x * x);
    return 0.5f * x * (1.0f + tanhf(c));
}

// ---------------- weight transpose + bf16 cast: Wt[c][r] = bf16(W[r][c]) ----
__global__ __launch_bounds__(256) void wt_kernel(const float* __restrict__ W,
                                                 u16* __restrict__ Wt, int R, int C) {
    __shared__ float tile[32][33];
    int c0 = blockIdx.x * 32, r0 = blockIdx.y * 32;
    int tx = threadIdx.x & 31, ty = threadIdx.x >> 5;   // ty in [0,8)
#pragma unroll
    for (int i = 0; i < 32; i += 8)
        tile[ty + i][tx] = W[(size_t)(r0 + ty + i) * C + c0 + tx];
    __syncthreads();
#pragma unroll
    for (int i = 0; i < 32; i += 8)
        Wt[(size_t)(c0 + ty + i) * R + r0 + tx] = f2bf(tile[tx][ty + i]);
}

// ---------------- LayerNorm over D=1024, fp32 in -> bf16 out ----------------
__global__ __launch_bounds__(256) void ln1024(const float* __restrict__ x,
                                              const float* __restrict__ s,
                                              const float* __restrict__ bi,
                                              u16* __restrict__ out) {
    int row = blockIdx.x, t = threadIdx.x;
    const float4* xr = (const float4*)(x + (size_t)row * 1024);
    float4 v = xr[t];
    float sum = v.x + v.y + v.z + v.w;
    float sq  = v.x * v.x + v.y * v.y + v.z * v.z + v.w * v.w;
#pragma unroll
    for (int off = 1; off < 64; off <<= 1) {
        sum += __shfl_xor(sum, off);
        sq  += __shfl_xor(sq,  off);
    }
    __shared__ float s1[4], s2[4];
    int wave = t >> 6;
    if ((t & 63) == 0) { s1[wave] = sum; s2[wave] = sq; }
    __syncthreads();
    sum = s1[0] + s1[1] + s1[2] + s1[3];
    sq  = s2[0] + s2[1] + s2[2] + s2[3];
    float mean = sum * (1.0f / 1024.0f);
    float var  = sq  * (1.0f / 1024.0f) - mean * mean;
    float inv  = rsqrtf(var + 1e-6f);
    float4 sc = ((const float4*)s)[t], bb = ((const float4*)bi)[t];
    u16x4 o;
    o[0] = f2bf((v.x - mean) * inv * sc.x + bb.x);
    o[1] = f2bf((v.y - mean) * inv * sc.y + bb.y);
    o[2] = f2bf((v.z - mean) * inv * sc.z + bb.z);
    o[3] = f2bf((v.w - mean) * inv * sc.w + bb.w);
    *(u16x4*)&out[(size_t)row * 1024 + t * 4] = o;
}

// ---------------- QK-norm: LN over DH=64 per (b,s,h), in-place bf16 ---------
// postscale folds the 1/sqrt(DH) attention scale into q.
__global__ __launch_bounds__(256) void qknorm(u16* __restrict__ q,
                                              const float* __restrict__ s,
                                              const float* __restrict__ b,
                                              float postscale) {
    int gid  = blockIdx.x * 4 + (threadIdx.x >> 6);  // one wave per (b,s,h) row
    int lane = threadIdx.x & 63;
    size_t base = (size_t)gid * 64;
    float v = bf2f(q[base + lane]);
    float sum = v, sq = v * v;
#pragma unroll
    for (int off = 1; off < 64; off <<= 1) {
        sum += __shfl_xor(sum, off);
        sq  += __shfl_xor(sq,  off);
    }
    float mean = sum * (1.0f / 64.0f);
    float var  = sq  * (1.0f / 64.0f) - mean * mean;
    float inv  = rsqrtf(var + 1e-6f);
    int h = gid & 15;
    float o = (v - mean) * inv * s[h * 64 + lane] + b[h * 64 + lane];
    q[base + lane] = f2bf(o * postscale);
}

// ---------------- GEMM: C[M,N] = A[M,K] @ Bt[N,K]^T, bf16 MFMA, fp32 acc ----
// EPI 0: fp32 = acc+bias | 1: bf16 = acc+bias | 2: fp32 = acc+bias+res
// EPI 3: bf16 = bf(res16) * gelu(acc+bias)   (GeGLU fused; res is bf16 x1)
#define BM 128
#define BN 128
#define BK 32
template <int EPI>
__global__ __launch_bounds__(256) void gemm_bt(const u16* __restrict__ A,
                                               const u16* __restrict__ Bt,
                                               const float* __restrict__ bias,
                                               const float* __restrict__ res,
                                               void* __restrict__ Cout,
                                               int M, int N, int K) {
    __shared__ u16 As[BM * BK];   // [row][k]
    __shared__ u16 Bs[BN * BK];   // [col][k]
    int tid = threadIdx.x, wave = tid >> 6, lane = tid & 63;
    int quad = lane >> 4, l15 = lane & 15;
    int row0 = blockIdx.y * BM, col0 = blockIdx.x * BN;
    int wm = wave >> 1, wn = wave & 1;

    f32x4 acc[4][4] = {};

    const u16* gA = A  + (size_t)(row0 + wave * 32 + (lane >> 2)) * K + (lane & 3) * 8;
    const u16* gB = Bt + (size_t)(col0 + wave * 32 + (lane >> 2)) * K + (lane & 3) * 8;
    u16* lA = &As[wave * 32 * BK];
    u16* lB = &Bs[wave * 32 * BK];

    for (int k0 = 0; k0 < K; k0 += BK) {
        __syncthreads();                       // LDS reuse guard
        g2l16(gA + k0,            lA);         // rows [w*32, w*32+16)
        g2l16(gA + k0 + 16 * K,   lA + 16 * BK);
        g2l16(gB + k0,            lB);
        g2l16(gB + k0 + 16 * K,   lB + 16 * BK);
        __syncthreads();                       // staging visible (vmcnt drained)
        bfrag af[4], bf[4];
#pragma unroll
        for (int mi = 0; mi < 4; mi++)
            af[mi] = *(const bfrag*)&As[(wm * 64 + mi * 16 + l15) * BK + quad * 8];
#pragma unroll
        for (int ni = 0; ni < 4; ni++)
            bf[ni] = *(const bfrag*)&Bs[(wn * 64 + ni * 16 + l15) * BK + quad * 8];
#pragma unroll
        for (int mi = 0; mi < 4; mi++)
#pragma unroll
            for (int ni = 0; ni < 4; ni++)
                acc[mi][ni] = __builtin_amdgcn_mfma_f32_16x16x32_bf16(
                    af[mi], bf[ni], acc[mi][ni], 0, 0, 0);
    }

    // epilogue
    float bv[4];
    int cols[4];
#pragma unroll
    for (int ni = 0; ni < 4; ni++) {
        cols[ni] = col0 + wn * 64 + ni * 16 + l15;
        bv[ni]   = bias[cols[ni]];
    }
#pragma unroll
    for (int mi = 0; mi < 4; mi++) {
        int rbase = row0 + wm * 64 + mi * 16 + quad * 4;
#pragma unroll
        for (int r = 0; r < 4; r++) {
            int row = rbase + r;
#pragma unroll
            for (int ni = 0; ni < 4; ni++) {
                float val = acc[mi][ni][r] + bv[ni];
                size_t idx = (size_t)row * N + cols[ni];
                if (EPI == 0) {
                    ((float*)Cout)[idx] = val;
                } else if (EPI == 1) {
                    ((u16*)Cout)[idx] = f2bf(val);
                } else if (EPI == 2) {
                    ((float*)Cout)[idx] = val + res[idx];
                } else {  // EPI == 3: GeGLU
                    float x1 = bf2f(((const u16*)res)[idx]);
                    ((u16*)Cout)[idx] = f2bf(x1 * gelu_tanh(val));
                }
            }
        }
    }
}

// ---------------- Flash attention: bf16 QKV (B,S,H,DH), bf16 out ------------
// grid (S/128, H, B); 256 threads; Q pre-scaled by 1/sqrt(DH) in qknorm.
__global__ __launch_bounds__(256) void flash(const u16* __restrict__ q,
                                             const u16* __restrict__ k,
                                             const u16* __restrict__ v,
                                             u16* __restrict__ o) {
    int qt = blockIdx.x, h = blockIdx.y, b = blockIdx.z;
    int tid = threadIdx.x, wave = tid >> 6, lane = tid & 63;
    int quad = lane >> 4, l15 = lane & 15;

    __shared__ u16 Qs[128 * 64];   // [qrow][d]
    __shared__ u16 Ks[64 * 64];    // [key][d]
    __shared__ u16 Vs[64 * 64];    // [key][d]
    __shared__ u16 Ps[128 * 64];   // [qrow][key] — wave-private row blocks

    // load Q tile (rows qt*128 .. +128)
    {
        int row = tid >> 1, half = tid & 1;
        const u16* src = q + ((size_t)(b * 1024 + qt * 128 + row) * 16 + h) * 64 + half * 32;
        u16* dst = &Qs[row * 64 + half * 32];
#pragma unroll
        for (int i = 0; i < 4; i++)
            ((u16x8*)dst)[i] = ((const u16x8*)src)[i];
    }

    f32x4 accO[2][4] = {};
    float m_run[2][4], l_run[2][4];
#pragma unroll
    for (int rt = 0; rt < 2; rt++)
#pragma unroll
        for (int r = 0; r < 4; r++) { m_run[rt][r] = -1e30f; l_run[rt][r] = 0.0f; }

    for (int kt = 0; kt < 16; kt++) {
        __syncthreads();   // prev iteration done reading Ks/Vs
        {
            int row = tid >> 2, seg = tid & 3;   // 64 rows, 16 elems per thread
            size_t gbase = ((size_t)(b * 1024 + kt * 64 + row) * 16 + h) * 64 + seg * 16;
            ((u16x8*)&Ks[row * 64 + seg * 16])[0] = ((const u16x8*)&k[gbase])[0];
            ((u16x8*)&Ks[row * 64 + seg * 16])[1] = ((const u16x8*)&k[gbase])[1];
            ((u16x8*)&Vs[row * 64 + seg * 16])[0] = ((const u16x8*)&v[gbase])[0];
            ((u16x8*)&Vs[row * 64 + seg * 16])[1] = ((const u16x8*)&v[gbase])[1];
        }
        __syncthreads();

        // phase A: S = Q(32 own rows) x K^T(64 keys)
        f32x4 accS[2][4] = {};
#pragma unroll
        for (int kk = 0; kk < 2; kk++) {
            bfrag aq[2];
#pragma unroll
            for (int rt = 0; rt < 2; rt++)
                aq[rt] = *(const bfrag*)&Qs[(wave * 32 + rt * 16 + l15) * 64 + kk * 32 + quad * 8];
#pragma unroll
            for (int ct = 0; ct < 4; ct++) {
                bfrag bk = *(const bfrag*)&Ks[(ct * 16 + l15) * 64 + kk * 32 + quad * 8];
                accS[0][ct] = __builtin_amdgcn_mfma_f32_16x16x32_bf16(aq[0], bk, accS[0][ct], 0, 0, 0);
                accS[1][ct] = __builtin_amdgcn_mfma_f32_16x16x32_bf16(aq[1], bk, accS[1][ct], 0, 0, 0);
            }
        }

        // online softmax, write P (wave-private rows, no barrier needed)
#pragma unroll
        for (int rt = 0; rt < 2; rt++) {
#pragma unroll
            for (int r = 0; r < 4; r++) {
                float tmax = accS[rt][0][r];
#pragma unroll
                for (int ct = 1; ct < 4; ct++) tmax = fmaxf(tmax, accS[rt][ct][r]);
#pragma unroll
                for (int m = 1; m < 16; m <<= 1) tmax = fmaxf(tmax, __shfl_xor(tmax, m));
                float mnew  = fmaxf(m_run[rt][r], tmax);
                float alpha = __expf(m_run[rt][r] - mnew);
                float lsum = 0.0f;
                float p[4];
#pragma unroll
                for (int ct = 0; ct < 4; ct++) {
                    p[ct] = __expf(accS[rt][ct][r] - mnew);
                    lsum += p[ct];
                }
#pragma unroll
                for (int m = 1; m < 16; m <<= 1) lsum += __shfl_xor(lsum, m);
                l_run[rt][r] = l_run[rt][r] * alpha + lsum;
                m_run[rt][r] = mnew;
#pragma unroll
                for (int oc = 0; oc < 4; oc++) accO[rt][oc][r] *= alpha;
                int prow = wave * 32 + rt * 16 + quad * 4 + r;
#pragma unroll
                for (int ct = 0; ct < 4; ct++)
                    Ps[prow * 64 + ct * 16 + l15] = f2bf(p[ct]);
            }
        }

        // phase B: O += P(32x64) x V(64x64)
#pragma unroll
        for (int kk = 0; kk < 2; kk++) {
            bfrag ap[2];
#pragma unroll
            for (int rt = 0; rt < 2; rt++)
                ap[rt] = *(const bfrag*)&Ps[(wave * 32 + rt * 16 + l15) * 64 + kk * 32 + quad * 8];
#pragma unroll
            for (int oc = 0; oc < 4; oc++) {
                bfrag bv;
#pragma unroll
                for (int j = 0; j < 8; j++)
                    bv[j] = *(const __bf16*)&Vs[(kk * 32 + quad * 8 + j) * 64 + oc * 16 + l15];
                accO[0][oc] = __builtin_amdgcn_mfma_f32_16x16x32_bf16(ap[0], bv, accO[0][oc], 0, 0, 0);
                accO[1][oc] = __builtin_amdgcn_mfma_f32_16x16x32_bf16(ap[1], bv, accO[1][oc], 0, 0, 0);
            }
        }
    }

    // epilogue: normalize and store bf16 (B,S,H,DH)
#pragma unroll
    for (int rt = 0; rt < 2; rt++) {
#pragma unroll
        for (int r = 0; r < 4; r++) {
            int srow = qt * 128 + wave * 32 + rt * 16 + quad * 4 + r;
            float linv = 1.0f / l_run[rt][r];
#pragma unroll
            for (int oc = 0; oc < 4; oc++)
                o[((size_t)(b * 1024 + srow) * 16 + h) * 64 + oc * 16 + l15] =
                    f2bf(accO[rt][oc][r] * linv);
        }
    }
}

// ---------------------------------------------------------------------------
extern "C" void kernel_launch(void* const* d_in, const int* in_sizes, int n_in,
                              void* d_out, int out_size, void* d_ws, size_t ws_size,
                              hipStream_t stream) {
    const float* x     = (const float*)d_in[0];
    const float* ln1_s = (const float*)d_in[2];
    const float* ln1_b = (const float*)d_in[3];
    const float* Wq = (const float*)d_in[4];  const float* bq = (const float*)d_in[5];
    const float* Wk = (const float*)d_in[6];  const float* bk = (const float*)d_in[7];
    const float* Wv = (const float*)d_in[8];  const float* bv = (const float*)d_in[9];
    const float* qn_s = (const float*)d_in[10]; const float* qn_b = (const float*)d_in[11];
    const float* kn_s = (const float*)d_in[12]; const float* kn_b = (const float*)d_in[13];
    const float* Wo = (const float*)d_in[14]; const float* bo = (const float*)d_in[15];
    const float* ln2_s = (const float*)d_in[16]; const float* ln2_b = (const float*)d_in[17];
    const float* W1 = (const float*)d_in[18]; const float* b1 = (const float*)d_in[19];
    const float* W2 = (const float*)d_in[20]; const float* b2 = (const float*)d_in[21];
    const float* W3 = (const float*)d_in[22]; const float* b3 = (const float*)d_in[23];
    float* out = (float*)d_out;

    char* ws = (char*)d_ws;
    const size_t MB = (size_t)1 << 20;
    u16* WqT = (u16*)(ws + 0 * MB);    // 2 MB each (1024x1024 bf16)
    u16* WkT = (u16*)(ws + 2 * MB);
    u16* WvT = (u16*)(ws + 4 * MB);
    u16* WoT = (u16*)(ws + 6 * MB);
    u16* W1T = (u16*)(ws + 8 * MB);    // 8 MB (4096x1024 bf16)
    u16* W2T = (u16*)(ws + 16 * MB);   // 8 MB
    u16* W3T = (u16*)(ws + 24 * MB);   // 8 MB (1024x4096 bf16)
    u16* xn1 = (u16*)(ws + 32 * MB);   // 8 MB; later reused as attn_out
    u16* qb  = (u16*)(ws + 40 * MB);   // 8 MB
    u16* kb  = (u16*)(ws + 48 * MB);   // 8 MB
    float* xmid = (float*)(ws + 40 * MB); // 16 MB, aliases qb+kb (dead after flash)
    u16* vb  = (u16*)(ws + 56 * MB);   // 8 MB; later reused as xn2
    u16* xn2 = (u16*)(ws + 56 * MB);
    u16* x1b = (u16*)(ws + 64 * MB);   // 32 MB (4096x4096 bf16); h written in place
    // total: 96 MB

    dim3 blk(256);

    // weight transposes (fp32 -> bf16 W^T)
    wt_kernel<<<dim3(32, 32),  blk, 0, stream>>>(Wq, WqT, 1024, 1024);
    wt_kernel<<<dim3(32, 32),  blk, 0, stream>>>(Wk, WkT, 1024, 1024);
    wt_kernel<<<dim3(32, 32),  blk, 0, stream>>>(Wv, WvT, 1024, 1024);
    wt_kernel<<<dim3(32, 32),  blk, 0, stream>>>(Wo, WoT, 1024, 1024);
    wt_kernel<<<dim3(128, 32), blk, 0, stream>>>(W1, W1T, 1024, 4096);
    wt_kernel<<<dim3(128, 32), blk, 0, stream>>>(W2, W2T, 1024, 4096);
    wt_kernel<<<dim3(32, 128), blk, 0, stream>>>(W3, W3T, 4096, 1024);

    // LN1 -> xn1 (bf16)
    ln1024<<<4096, blk, 0, stream>>>(x, ln1_s, ln1_b, xn1);

    // QKV projections (bf16 out + bias)
    gemm_bt<1><<<dim3(8, 32), blk, 0, stream>>>(xn1, WqT, bq, nullptr, qb, 4096, 1024, 1024);
    gemm_bt<1><<<dim3(8, 32), blk, 0, stream>>>(xn1, WkT, bk, nullptr, kb, 4096, 1024, 1024);
    gemm_bt<1><<<dim3(8, 32), blk, 0, stream>>>(xn1, WvT, bv, nullptr, vb, 4096, 1024, 1024);

    // QK-norm in place; fold 1/sqrt(64) into q
    qknorm<<<16384, blk, 0, stream>>>(qb, qn_s, qn_b, 0.125f);
    qknorm<<<16384, blk, 0, stream>>>(kb, kn_s, kn_b, 1.0f);

    // attention -> attn_out (reuses xn1 buffer)
    flash<<<dim3(8, 16, 4), blk, 0, stream>>>(qb, kb, vb, xn1);

    // out projection + residual: xmid = x + attn @ Wo + bo
    gemm_bt<2><<<dim3(8, 32), blk, 0, stream>>>(xn1, WoT, bo, x, xmid, 4096, 1024, 1024);

    // LN2 -> xn2 (bf16)
    ln1024<<<4096, blk, 0, stream>>>(xmid, ln2_s, ln2_b, xn2);

    // FFN: x1 = xn2@W1+b1 (bf16); h = x1 * gelu(xn2@W2+b2) fused into second GEMM
    gemm_bt<1><<<dim3(32, 32), blk, 0, stream>>>(xn2, W1T, b1, nullptr, x1b, 4096, 4096, 1024);
    gemm_bt<3><<<dim3(32, 32), blk, 0, stream>>>(xn2, W2T, b2, (const float*)x1b, x1b, 4096, 4096, 1024);

    // out = xmid + h @ W3 + b3
    gemm_bt<2><<<dim3(8, 32), blk, 0, stream>>>(x1b, W3T, b3, xmid, out, 4096, 1024, 4096);
}

// Round 2
// 526.051 us; speedup vs baseline: 1.1955x; 1.1955x over previous
//
#include <hip/hip_runtime.h>

typedef unsigned short u16;
typedef __bf16  bfrag  __attribute__((ext_vector_type(8)));   // MFMA A/B operand (4 VGPRs)
typedef float   f32x4  __attribute__((ext_vector_type(4)));   // MFMA C/D operand
typedef u16     u16x8  __attribute__((ext_vector_type(8)));
typedef u16     u16x4  __attribute__((ext_vector_type(4)));

__device__ __forceinline__ float bf2f(u16 u) {
    unsigned v = ((unsigned)u) << 16;
    return __builtin_bit_cast(float, v);
}
__device__ __forceinline__ u16 f2bf(float f) {   // round-to-nearest-even
    unsigned x = __builtin_bit_cast(unsigned, f);
    unsigned r = (x + 0x7fffu + ((x >> 16) & 1u)) >> 16;
    return (u16)r;
}
__device__ __forceinline__ void g2l16(const u16* g, u16* l) {
    // 16B per lane -> lds_base + lane*16 (wave-uniform LDS base)
    __builtin_amdgcn_global_load_lds((__attribute__((address_space(1))) void*)g,
                                     (__attribute__((address_space(3))) void*)l, 16, 0, 0);
}
__device__ __forceinline__ float gelu_tanh(float x) {
    float c = 0.7978845608028654f * (x + 0.044715f * x * x * x);
    return 0.5f * x * (1.0f + tanhf(c));
}

// ---------------- all 7 weight transposes in ONE kernel ---------------------
// Wt[c][r] = bf16(W[r][c]).  Block ranges hardcoded for this problem's shapes.
__global__ __launch_bounds__(256) void wt_all(
        const float* __restrict__ Wq, const float* __restrict__ Wk,
        const float* __restrict__ Wv, const float* __restrict__ Wo,
        const float* __restrict__ W1, const float* __restrict__ W2,
        const float* __restrict__ W3,
        u16* __restrict__ WqkvT, u16* __restrict__ WoT,
        u16* __restrict__ W1T, u16* __restrict__ W2T, u16* __restrict__ W3T) {
    int blk = blockIdx.x;
    const float* W; u16* Wt; int R, C, local;
    if (blk < 3072) {          // Wq/Wk/Wv -> packed WqkvT [3072][1024]
        int w = blk >> 10; local = blk & 1023;
        W = (w == 0) ? Wq : (w == 1) ? Wk : Wv;
        Wt = WqkvT + (size_t)w * 1024 * 1024; R = 1024; C = 1024;
    } else if (blk < 4096) { W = Wo; Wt = WoT; R = 1024; C = 1024; local = blk - 3072; }
    else if (blk < 8192)   { W = W1; Wt = W1T; R = 1024; C = 4096; local = blk - 4096; }
    else if (blk < 12288)  { W = W2; Wt = W2T; R = 1024; C = 4096; local = blk - 8192; }
    else                   { W = W3; Wt = W3T; R = 4096; C = 1024; local = blk - 12288; }
    int tiles_x = C >> 5;
    int c0 = (local % tiles_x) * 32, r0 = (local / tiles_x) * 32;

    __shared__ float tile[32][33];
    int tx = threadIdx.x & 31, ty = threadIdx.x >> 5;   // ty in [0,8)
#pragma unroll
    for (int i = 0; i < 32; i += 8)
        tile[ty + i][tx] = W[(size_t)(r0 + ty + i) * C + c0 + tx];
    __syncthreads();
#pragma unroll
    for (int i = 0; i < 32; i += 8)
        Wt[(size_t)(c0 + ty + i) * R + r0 + tx] = f2bf(tile[tx][ty + i]);
}

// ---------------- LayerNorm over D=1024, fp32 in -> bf16 out ----------------
__global__ __launch_bounds__(256) void ln1024(const float* __restrict__ x,
                                              const float* __restrict__ s,
                                              const float* __restrict__ bi,
                                              u16* __restrict__ out) {
    int row = blockIdx.x, t = threadIdx.x;
    const float4* xr = (const float4*)(x + (size_t)row * 1024);
    float4 v = xr[t];
    float sum = v.x + v.y + v.z + v.w;
    float sq  = v.x * v.x + v.y * v.y + v.z * v.z + v.w * v.w;
#pragma unroll
    for (int off = 1; off < 64; off <<= 1) {
        sum += __shfl_xor(sum, off);
        sq  += __shfl_xor(sq,  off);
    }
    __shared__ float s1[4], s2[4];
    int wave = t >> 6;
    if ((t & 63) == 0) { s1[wave] = sum; s2[wave] = sq; }
    __syncthreads();
    sum = s1[0] + s1[1] + s1[2] + s1[3];
    sq  = s2[0] + s2[1] + s2[2] + s2[3];
    float mean = sum * (1.0f / 1024.0f);
    float var  = sq  * (1.0f / 1024.0f) - mean * mean;
    float inv  = rsqrtf(var + 1e-6f);
    float4 sc = ((const float4*)s)[t], bb = ((const float4*)bi)[t];
    u16x4 o;
    o[0] = f2bf((v.x - mean) * inv * sc.x + bb.x);
    o[1] = f2bf((v.y - mean) * inv * sc.y + bb.y);
    o[2] = f2bf((v.z - mean) * inv * sc.z + bb.z);
    o[3] = f2bf((v.w - mean) * inv * sc.w + bb.w);
    *(u16x4*)&out[(size_t)row * 1024 + t * 4] = o;
}

// ---------------- fused QK-norm on the packed qkv buffer --------------------
// qkv layout [4096 tokens][3072]; q at +0, k at +1024. One wave per (t,z,h).
__global__ __launch_bounds__(256) void qknorm2(u16* __restrict__ qkv,
                                               const float* __restrict__ qn_s,
                                               const float* __restrict__ qn_b,
                                               const float* __restrict__ kn_s,
                                               const float* __restrict__ kn_b) {
    int gid  = blockIdx.x * 4 + (threadIdx.x >> 6);   // [0, 131072)
    int lane = threadIdx.x & 63;
    int tok = gid >> 5, rem = gid & 31, z = rem >> 4, h = rem & 15;
    size_t base = (size_t)tok * 3072 + z * 1024 + h * 64;
    float v = bf2f(qkv[base + lane]);
    float sum = v, sq = v * v;
#pragma unroll
    for (int off = 1; off < 64; off <<= 1) {
        sum += __shfl_xor(sum, off);
        sq  += __shfl_xor(sq,  off);
    }
    float mean = sum * (1.0f / 64.0f);
    float var  = sq  * (1.0f / 64.0f) - mean * mean;
    float inv  = rsqrtf(var + 1e-6f);
    const float* s = z ? kn_s : qn_s;
    const float* b = z ? kn_b : qn_b;
    float post = z ? 1.0f : 0.125f;   // fold 1/sqrt(DH) into q
    float o = ((v - mean) * inv * s[h * 64 + lane] + b[h * 64 + lane]) * post;
    qkv[base + lane] = f2bf(o);
}

// ---------------- GEMM: C[M,N] = A[M,K] @ Bt[N,K]^T, bf16 MFMA, fp32 acc ----
// LDS layout XOR-swizzled: phys_seg = log_seg ^ (row&3)  (seg = 16B chunk of
// the 64B row). Staging picks the per-lane GLOBAL source to match; fragment
// reads XOR the offset. Cuts the 8-way frag-read bank conflict to 4-way.
// EPI 0: fp32=acc+bias | 1: bf16=acc+bias | 2: fp32=acc+bias+res
// EPI 3: bf16 = bf(res16) * gelu(acc+bias)   (GeGLU; res is bf16 x1)
// BSEL 1: bias is 3 packed segments (bias/bias2/bias3 each 1024 wide)
#define BM 128
#define BK 32
template <int EPI, int BN_, int BSEL>
__global__ __launch_bounds__(256) void gemm_bt(const u16* __restrict__ A,
                                               const u16* __restrict__ Bt,
                                               const float* __restrict__ bias,
                                               const float* __restrict__ bias2,
                                               const float* __restrict__ bias3,
                                               const float* __restrict__ res,
                                               void* __restrict__ Cout,
                                               int M, int N, int K) {
    __shared__ u16 As[BM * BK];
    __shared__ u16 Bs[BN_ * BK];
    constexpr int MI = (BN_ == 128) ? 4 : 2;   // 16-row frags per wave
    constexpr int NI = 4;                       // 16-col frags per wave
    int tid = threadIdx.x, wave = tid >> 6, lane = tid & 63;
    int quad = lane >> 4, l15 = lane & 15;
    int row0 = blockIdx.y * BM, col0 = blockIdx.x * BN_;
    int wr = (BN_ == 128) ? (wave >> 1) * 64 : wave * 32;   // wave row base
    int wc = (BN_ == 128) ? (wave & 1) * 64 : 0;            // wave col base
    int swz = ((lane & 3) ^ ((lane >> 2) & 3)) * 8;         // staging k-offset
    int rswz = (quad ^ (l15 & 3)) * 8;                      // frag-read k-offset

    f32x4 acc[MI][NI] = {};

    const u16* gA = A + (size_t)(row0 + wave * 32 + (lane >> 2)) * K + swz;
    u16* lA = &As[wave * 32 * BK];
    const u16* gB;
    u16* lB;
    if (BN_ == 128) { gB = Bt + (size_t)(col0 + wave * 32 + (lane >> 2)) * K + swz; lB = &Bs[wave * 32 * BK]; }
    else            { gB = Bt + (size_t)(col0 + wave * 16 + (lane >> 2)) * K + swz; lB = &Bs[wave * 16 * BK]; }

    for (int k0 = 0; k0 < K; k0 += BK) {
        __syncthreads();
        g2l16(gA + k0,          lA);
        g2l16(gA + k0 + 16 * K, lA + 16 * BK);
        if (BN_ == 128) {
            g2l16(gB + k0,          lB);
            g2l16(gB + k0 + 16 * K, lB + 16 * BK);
        } else {
            g2l16(gB + k0, lB);
        }
        __syncthreads();
        bfrag af[MI], bf[NI];
#pragma unroll
        for (int mi = 0; mi < MI; mi++)
            af[mi] = *(const bfrag*)&As[(wr + mi * 16 + l15) * BK + rswz];
#pragma unroll
        for (int ni = 0; ni < NI; ni++)
            bf[ni] = *(const bfrag*)&Bs[(wc + ni * 16 + l15) * BK + rswz];
#pragma unroll
        for (int mi = 0; mi < MI; mi++)
#pragma unroll
            for (int ni = 0; ni < NI; ni++)
                acc[mi][ni] = __builtin_amdgcn_mfma_f32_16x16x32_bf16(
                    af[mi], bf[ni], acc[mi][ni], 0, 0, 0);
    }

    float bv[NI];
    int cols[NI];
#pragma unroll
    for (int ni = 0; ni < NI; ni++) {
        cols[ni] = col0 + wc + ni * 16 + l15;
        if (BSEL == 1) {
            int seg = cols[ni] >> 10;
            const float* bp = (seg == 0) ? bias : (seg == 1) ? bias2 : bias3;
            bv[ni] = bp[cols[ni] & 1023];
        } else {
            bv[ni] = bias[cols[ni]];
        }
    }
#pragma unroll
    for (int mi = 0; mi < MI; mi++) {
        int rbase = row0 + wr + mi * 16 + quad * 4;
#pragma unroll
        for (int r = 0; r < 4; r++) {
            int row = rbase + r;
#pragma unroll
            for (int ni = 0; ni < NI; ni++) {
                float val = acc[mi][ni][r] + bv[ni];
                size_t idx = (size_t)row * N + cols[ni];
                if (EPI == 0) {
                    ((float*)Cout)[idx] = val;
                } else if (EPI == 1) {
                    ((u16*)Cout)[idx] = f2bf(val);
                } else if (EPI == 2) {
                    ((float*)Cout)[idx] = val + res[idx];
                } else {
                    float x1 = bf2f(((const u16*)res)[idx]);
                    ((u16*)Cout)[idx] = f2bf(x1 * gelu_tanh(val));
                }
            }
        }
    }
}

// ---------------- Flash attention on packed qkv [4096][3072] ----------------
// grid (S/128, H, B); 256 threads. Q pre-scaled by 1/sqrt(DH) in qknorm2.
// All LDS rows padded to 72 u16 (144 B): frag reads 2-way (free), writes 8-way.
// V staged TRANSPOSED (Vt[d][key]) so PV B-fragments are ds_read_b128.
#define LP 72
__global__ __launch_bounds__(256) void flash(const u16* __restrict__ qkv,
                                             u16* __restrict__ o) {
    int qt = blockIdx.x, h = blockIdx.y, b = blockIdx.z;
    int tid = threadIdx.x, wave = tid >> 6, lane = tid & 63;
    int quad = lane >> 4, l15 = lane & 15;

    __shared__ u16 Qs[128 * LP];
    __shared__ u16 Ks[64 * LP];
    __shared__ u16 Vt[64 * LP];   // [d][key]
    __shared__ u16 Ps[128 * LP];

    {   // Q tile: rows qt*128 .. +128
        int row = tid >> 1, half = tid & 1;
        const u16* src = qkv + (size_t)(b * 1024 + qt * 128 + row) * 3072 + h * 64 + half * 32;
        u16* dst = &Qs[row * LP + half * 32];
#pragma unroll
        for (int i = 0; i < 4; i++)
            ((u16x8*)dst)[i] = ((const u16x8*)src)[i];
    }

    f32x4 accO[2][4] = {};
    float m_run[2][4], l_run[2][4];
#pragma unroll
    for (int rt = 0; rt < 2; rt++)
#pragma unroll
        for (int r = 0; r < 4; r++) { m_run[rt][r] = -1e30f; l_run[rt][r] = 0.0f; }

    for (int kt = 0; kt < 16; kt++) {
        __syncthreads();
        {   // K rows + V transposed
            int row = tid >> 2, seg = tid & 3;
            size_t gb = (size_t)(b * 1024 + kt * 64 + row) * 3072 + h * 64;
            const u16* ksrc = qkv + gb + 1024 + seg * 16;
            *(u16x8*)&Ks[row * LP + seg * 16]     = *(const u16x8*)ksrc;
            *(u16x8*)&Ks[row * LP + seg * 16 + 8] = *(const u16x8*)(ksrc + 8);
            const u16* vsrc = qkv + gb + 2048 + seg * 16;
            u16x8 v0 = *(const u16x8*)vsrc, v1 = *(const u16x8*)(vsrc + 8);
#pragma unroll
            for (int j = 0; j < 8; j++) Vt[(seg * 16 + j) * LP + row]     = v0[j];
#pragma unroll
            for (int j = 0; j < 8; j++) Vt[(seg * 16 + 8 + j) * LP + row] = v1[j];
        }
        __syncthreads();

        // phase A: S = Q(own 32 rows) x K^T(64 keys)
        f32x4 accS[2][4] = {};
#pragma unroll
        for (int kk = 0; kk < 2; kk++) {
            bfrag aq[2];
#pragma unroll
            for (int rt = 0; rt < 2; rt++)
                aq[rt] = *(const bfrag*)&Qs[(wave * 32 + rt * 16 + l15) * LP + kk * 32 + quad * 8];
#pragma unroll
            for (int ct = 0; ct < 4; ct++) {
                bfrag bk = *(const bfrag*)&Ks[(ct * 16 + l15) * LP + kk * 32 + quad * 8];
                accS[0][ct] = __builtin_amdgcn_mfma_f32_16x16x32_bf16(aq[0], bk, accS[0][ct], 0, 0, 0);
                accS[1][ct] = __builtin_amdgcn_mfma_f32_16x16x32_bf16(aq[1], bk, accS[1][ct], 0, 0, 0);
            }
        }

        // online softmax; P written to wave-private Ps rows (no barrier)
#pragma unroll
        for (int rt = 0; rt < 2; rt++) {
#pragma unroll
            for (int r = 0; r < 4; r++) {
                float tmax = accS[rt][0][r];
#pragma unroll
                for (int ct = 1; ct < 4; ct++) tmax = fmaxf(tmax, accS[rt][ct][r]);
#pragma unroll
                for (int m = 1; m < 16; m <<= 1) tmax = fmaxf(tmax, __shfl_xor(tmax, m));
                float mnew  = fmaxf(m_run[rt][r], tmax);
                float alpha = __expf(m_run[rt][r] - mnew);
                float lsum = 0.0f;
                float p[4];
#pragma unroll
                for (int ct = 0; ct < 4; ct++) {
                    p[ct] = __expf(accS[rt][ct][r] - mnew);
                    lsum += p[ct];
                }
#pragma unroll
                for (int m = 1; m < 16; m <<= 1) lsum += __shfl_xor(lsum, m);
                l_run[rt][r] = l_run[rt][r] * alpha + lsum;
                m_run[rt][r] = mnew;
#pragma unroll
                for (int oc = 0; oc < 4; oc++) accO[rt][oc][r] *= alpha;
                int prow = wave * 32 + rt * 16 + quad * 4 + r;
#pragma unroll
                for (int ct = 0; ct < 4; ct++)
                    Ps[prow * LP + ct * 16 + l15] = f2bf(p[ct]);
            }
        }

        // phase B: O += P(32x64) x V(64x64), V-frags via b128 from Vt
#pragma unroll
        for (int kk = 0; kk < 2; kk++) {
            bfrag ap[2];
#pragma unroll
            for (int rt = 0; rt < 2; rt++)
                ap[rt] = *(const bfrag*)&Ps[(wave * 32 + rt * 16 + l15) * LP + kk * 32 + quad * 8];
#pragma unroll
            for (int oc = 0; oc < 4; oc++) {
                bfrag bv = *(const bfrag*)&Vt[(oc * 16 + l15) * LP + kk * 32 + quad * 8];
                accO[0][oc] = __builtin_amdgcn_mfma_f32_16x16x32_bf16(ap[0], bv, accO[0][oc], 0, 0, 0);
                accO[1][oc] = __builtin_amdgcn_mfma_f32_16x16x32_bf16(ap[1], bv, accO[1][oc], 0, 0, 0);
            }
        }
    }

    // epilogue: normalize, store bf16 into attn buffer [4096][1024]
#pragma unroll
    for (int rt = 0; rt < 2; rt++) {
#pragma unroll
        for (int r = 0; r < 4; r++) {
            int srow = qt * 128 + wave * 32 + rt * 16 + quad * 4 + r;
            float linv = 1.0f / l_run[rt][r];
#pragma unroll
            for (int oc = 0; oc < 4; oc++)
                o[(size_t)(b * 1024 + srow) * 1024 + h * 64 + oc * 16 + l15] =
                    f2bf(accO[rt][oc][r] * linv);
        }
    }
}

// ---------------------------------------------------------------------------
extern "C" void kernel_launch(void* const* d_in, const int* in_sizes, int n_in,
                              void* d_out, int out_size, void* d_ws, size_t ws_size,
                              hipStream_t stream) {
    const float* x     = (const float*)d_in[0];
    const float* ln1_s = (const float*)d_in[2];
    const float* ln1_b = (const float*)d_in[3];
    const float* Wq = (const float*)d_in[4];  const float* bq = (const float*)d_in[5];
    const float* Wk = (const float*)d_in[6];  const float* bk = (const float*)d_in[7];
    const float* Wv = (const float*)d_in[8];  const float* bv = (const float*)d_in[9];
    const float* qn_s = (const float*)d_in[10]; const float* qn_b = (const float*)d_in[11];
    const float* kn_s = (const float*)d_in[12]; const float* kn_b = (const float*)d_in[13];
    const float* Wo = (const float*)d_in[14]; const float* bo = (const float*)d_in[15];
    const float* ln2_s = (const float*)d_in[16]; const float* ln2_b = (const float*)d_in[17];
    const float* W1 = (const float*)d_in[18]; const float* b1 = (const float*)d_in[19];
    const float* W2 = (const float*)d_in[20]; const float* b2 = (const float*)d_in[21];
    const float* W3 = (const float*)d_in[22]; const float* b3 = (const float*)d_in[23];
    float* out = (float*)d_out;

    char* ws = (char*)d_ws;
    const size_t MB = (size_t)1 << 20;
    // lifetimes:  [launch order]
    u16* WqkvT = (u16*)(ws + 0 * MB);    // 6 MB  [3072][1024]   dead after QKV
    u16* WoT   = (u16*)(ws + 6 * MB);    // 2 MB                 dead after Wo
    u16* W1T   = (u16*)(ws + 8 * MB);    // 8 MB  [4096][1024]   dead after W1
    u16* W2T   = (u16*)(ws + 16 * MB);   // 8 MB                 dead after W2
    u16* W3T   = (u16*)(ws + 24 * MB);   // 8 MB  [1024][4096]   dead after W3
    u16* xn1   = (u16*)(ws + 33 * MB);   // 8 MB                 dead after QKV
    u16* attn  = (u16*)(ws + 33 * MB);   //   (reuse)            dead after Wo
    u16* xn2   = (u16*)(ws + 33 * MB);   //   (reuse after Wo)   dead after W2
    u16* qkv   = (u16*)(ws + 41 * MB);   // 24 MB [4096][3072]   dead after flash
    float* xmid = (float*)(ws + 41 * MB);// 16 MB (reuse qkv)    dead after W3
    u16* x1b   = (u16*)(ws + 64 * MB);   // 32 MB [4096][4096]   dead after W2 epi
    // peak = 96 MB

    dim3 blk(256);

    // wait — xn2 overlaps attn (input of Wo) only AFTER Wo completes; ln2 runs
    // after Wo, so the reuse is safe (stream-ordered).

    wt_all<<<16384, blk, 0, stream>>>(Wq, Wk, Wv, Wo, W1, W2, W3,
                                      WqkvT, WoT, W1T, W2T, W3T);

    ln1024<<<4096, blk, 0, stream>>>(x, ln1_s, ln1_b, xn1);

    // fused QKV: [4096,1024] @ [3072,1024]^T -> qkv [4096][3072]
    gemm_bt<1, 128, 1><<<dim3(24, 32), blk, 0, stream>>>(
        xn1, WqkvT, bq, bk, bv, nullptr, qkv, 4096, 3072, 1024);

    qknorm2<<<32768, blk, 0, stream>>>(qkv, qn_s, qn_b, kn_s, kn_b);

    flash<<<dim3(8, 16, 4), blk, 0, stream>>>(qkv, attn);

    // xmid = x + attn @ Wo + bo   (BN=64 -> 512 blocks)
    gemm_bt<2, 64, 0><<<dim3(16, 32), blk, 0, stream>>>(
        attn, WoT, bo, nullptr, nullptr, x, xmid, 4096, 1024, 1024);

    ln1024<<<4096, blk, 0, stream>>>(xmid, ln2_s, ln2_b, xn2);

    // x1 = xn2@W1+b1 (bf16)
    gemm_bt<1, 128, 0><<<dim3(32, 32), blk, 0, stream>>>(
        xn2, W1T, b1, nullptr, nullptr, nullptr, x1b, 4096, 4096, 1024);
    // h = x1 * gelu(xn2@W2+b2), in place over x1b
    gemm_bt<3, 128, 0><<<dim3(32, 32), blk, 0, stream>>>(
        xn2, W2T, b2, nullptr, nullptr, (const float*)x1b, x1b, 4096, 4096, 1024);

    // out = xmid + h @ W3 + b3   (K=4096, BN=64 -> 512 blocks)
    gemm_bt<2, 64, 0><<<dim3(16, 32), blk, 0, stream>>>(
        x1b, W3T, b3, nullptr, nullptr, xmid, out, 4096, 1024, 4096);
}

// Round 3
// 470.740 us; speedup vs baseline: 1.3360x; 1.1175x over previous
//
#include <hip/hip_runtime.h>

typedef unsigned short u16;
typedef __bf16  bfrag  __attribute__((ext_vector_type(8)));   // MFMA A/B operand (4 VGPRs)
typedef float   f32x4  __attribute__((ext_vector_type(4)));   // MFMA C/D operand
typedef u16     u16x8  __attribute__((ext_vector_type(8)));
typedef u16     u16x4  __attribute__((ext_vector_type(4)));

__device__ __forceinline__ float bf2f(u16 u) {
    unsigned v = ((unsigned)u) << 16;
    return __builtin_bit_cast(float, v);
}
__device__ __forceinline__ u16 f2bf(float f) {   // round-to-nearest-even
    unsigned x = __builtin_bit_cast(unsigned, f);
    unsigned r = (x + 0x7fffu + ((x >> 16) & 1u)) >> 16;
    return (u16)r;
}
__device__ __forceinline__ void g2l16(const u16* g, u16* l) {
    // 16B per lane -> lds_base + lane*16 (wave-uniform LDS base)
    __builtin_amdgcn_global_load_lds((__attribute__((address_space(1))) void*)g,
                                     (__attribute__((address_space(3))) void*)l, 16, 0, 0);
}
__device__ __forceinline__ float gelu_tanh(float x) {
    // 0.5x(1+tanh(c)) == x * sigmoid(2c)
    float c = 1.5957691216057308f * (x + 0.044715f * x * x * x);
    return x * __frcp_rn(1.0f + __expf(-c));
}

// ---------------- all 7 weight transposes in ONE kernel ---------------------
// Wt[c][r] = bf16(W[r][c]). W1/W2 pack into W12T [8192][1024].
__global__ __launch_bounds__(256) void wt_all(
        const float* __restrict__ Wq, const float* __restrict__ Wk,
        const float* __restrict__ Wv, const float* __restrict__ Wo,
        const float* __restrict__ W1, const float* __restrict__ W2,
        const float* __restrict__ W3,
        u16* __restrict__ WqkvT, u16* __restrict__ WoT,
        u16* __restrict__ W12T, u16* __restrict__ W3T) {
    int blk = blockIdx.x;
    const float* W; u16* Wt; int R, C, local;
    if (blk < 3072) {          // Wq/Wk/Wv -> packed WqkvT [3072][1024]
        int w = blk >> 10; local = blk & 1023;
        W = (w == 0) ? Wq : (w == 1) ? Wk : Wv;
        Wt = WqkvT + (size_t)w * 1024 * 1024; R = 1024; C = 1024;
    } else if (blk < 4096) { W = Wo; Wt = WoT; R = 1024; C = 1024; local = blk - 3072; }
    else if (blk < 8192)   { W = W1; Wt = W12T; R = 1024; C = 4096; local = blk - 4096; }
    else if (blk < 12288)  { W = W2; Wt = W12T + (size_t)4096 * 1024; R = 1024; C = 4096; local = blk - 8192; }
    else                   { W = W3; Wt = W3T; R = 4096; C = 1024; local = blk - 12288; }
    int tiles_x = C >> 5;
    int c0 = (local % tiles_x) * 32, r0 = (local / tiles_x) * 32;

    __shared__ float tile[32][33];
    int tx = threadIdx.x & 31, ty = threadIdx.x >> 5;   // ty in [0,8)
#pragma unroll
    for (int i = 0; i < 32; i += 8)
        tile[ty + i][tx] = W[(size_t)(r0 + ty + i) * C + c0 + tx];
    __syncthreads();
#pragma unroll
    for (int i = 0; i < 32; i += 8)
        Wt[(size_t)(c0 + ty + i) * R + r0 + tx] = f2bf(tile[tx][ty + i]);
}

// ---------------- LayerNorm over D=1024, fp32 in -> bf16 out ----------------
__global__ __launch_bounds__(256) void ln1024(const float* __restrict__ x,
                                              const float* __restrict__ s,
                                              const float* __restrict__ bi,
                                              u16* __restrict__ out) {
    int row = blockIdx.x, t = threadIdx.x;
    const float4* xr = (const float4*)(x + (size_t)row * 1024);
    float4 v = xr[t];
    float sum = v.x + v.y + v.z + v.w;
    float sq  = v.x * v.x + v.y * v.y + v.z * v.z + v.w * v.w;
#pragma unroll
    for (int off = 1; off < 64; off <<= 1) {
        sum += __shfl_xor(sum, off);
        sq  += __shfl_xor(sq,  off);
    }
    __shared__ float s1[4], s2[4];
    int wave = t >> 6;
    if ((t & 63) == 0) { s1[wave] = sum; s2[wave] = sq; }
    __syncthreads();
    sum = s1[0] + s1[1] + s1[2] + s1[3];
    sq  = s2[0] + s2[1] + s2[2] + s2[3];
    float mean = sum * (1.0f / 1024.0f);
    float var  = sq  * (1.0f / 1024.0f) - mean * mean;
    float inv  = rsqrtf(var + 1e-6f);
    float4 sc = ((const float4*)s)[t], bb = ((const float4*)bi)[t];
    u16x4 o;
    o[0] = f2bf((v.x - mean) * inv * sc.x + bb.x);
    o[1] = f2bf((v.y - mean) * inv * sc.y + bb.y);
    o[2] = f2bf((v.z - mean) * inv * sc.z + bb.z);
    o[3] = f2bf((v.w - mean) * inv * sc.w + bb.w);
    *(u16x4*)&out[(size_t)row * 1024 + t * 4] = o;
}

// ---------------- fused QK-norm on the packed qkv buffer --------------------
__global__ __launch_bounds__(256) void qknorm2(u16* __restrict__ qkv,
                                               const float* __restrict__ qn_s,
                                               const float* __restrict__ qn_b,
                                               const float* __restrict__ kn_s,
                                               const float* __restrict__ kn_b) {
    int gid  = blockIdx.x * 4 + (threadIdx.x >> 6);   // [0, 131072)
    int lane = threadIdx.x & 63;
    int tok = gid >> 5, rem = gid & 31, z = rem >> 4, h = rem & 15;
    size_t base = (size_t)tok * 3072 + z * 1024 + h * 64;
    float v = bf2f(qkv[base + lane]);
    float sum = v, sq = v * v;
#pragma unroll
    for (int off = 1; off < 64; off <<= 1) {
        sum += __shfl_xor(sum, off);
        sq  += __shfl_xor(sq,  off);
    }
    float mean = sum * (1.0f / 64.0f);
    float var  = sq  * (1.0f / 64.0f) - mean * mean;
    float inv  = rsqrtf(var + 1e-6f);
    const float* s = z ? kn_s : qn_s;
    const float* b = z ? kn_b : qn_b;
    float post = z ? 1.0f : 0.125f;   // fold 1/sqrt(DH) into q
    float o = ((v - mean) * inv * s[h * 64 + lane] + b[h * 64 + lane]) * post;
    qkv[base + lane] = f2bf(o);
}

// ---------------- GEMM: C[M,N] = A[M,K] @ Bt[N,K]^T, bf16 MFMA, fp32 acc ----
// XOR-swizzled LDS (phys_seg = log_seg ^ (row&3)).
// EPI 1: bf16=acc+bias | 2: fp32=acc+bias+res
// BSEL 1: bias is 3 packed 1024-wide segments
#define BM 128
#define BK 32
template <int EPI, int BN_, int BSEL>
__global__ __launch_bounds__(256) void gemm_bt(const u16* __restrict__ A,
                                               const u16* __restrict__ Bt,
                                               const float* __restrict__ bias,
                                               const float* __restrict__ bias2,
                                               const float* __restrict__ bias3,
                                               const float* __restrict__ res,
                                               void* __restrict__ Cout,
                                               int M, int N, int K) {
    __shared__ u16 As[BM * BK];
    __shared__ u16 Bs[BN_ * BK];
    constexpr int MI = (BN_ == 128) ? 4 : 2;
    constexpr int NI = 4;
    int tid = threadIdx.x, wave = tid >> 6, lane = tid & 63;
    int quad = lane >> 4, l15 = lane & 15;
    int row0 = blockIdx.y * BM, col0 = blockIdx.x * BN_;
    int wr = (BN_ == 128) ? (wave >> 1) * 64 : wave * 32;
    int wc = (BN_ == 128) ? (wave & 1) * 64 : 0;
    int swz = ((lane & 3) ^ ((lane >> 2) & 3)) * 8;
    int rswz = (quad ^ (l15 & 3)) * 8;

    f32x4 acc[MI][NI] = {};

    const u16* gA = A + (size_t)(row0 + wave * 32 + (lane >> 2)) * K + swz;
    u16* lA = &As[wave * 32 * BK];
    const u16* gB;
    u16* lB;
    if (BN_ == 128) { gB = Bt + (size_t)(col0 + wave * 32 + (lane >> 2)) * K + swz; lB = &Bs[wave * 32 * BK]; }
    else            { gB = Bt + (size_t)(col0 + wave * 16 + (lane >> 2)) * K + swz; lB = &Bs[wave * 16 * BK]; }

    for (int k0 = 0; k0 < K; k0 += BK) {
        __syncthreads();
        g2l16(gA + k0,          lA);
        g2l16(gA + k0 + 16 * K, lA + 16 * BK);
        if (BN_ == 128) {
            g2l16(gB + k0,          lB);
            g2l16(gB + k0 + 16 * K, lB + 16 * BK);
        } else {
            g2l16(gB + k0, lB);
        }
        __syncthreads();
        bfrag af[MI], bf[NI];
#pragma unroll
        for (int mi = 0; mi < MI; mi++)
            af[mi] = *(const bfrag*)&As[(wr + mi * 16 + l15) * BK + rswz];
#pragma unroll
        for (int ni = 0; ni < NI; ni++)
            bf[ni] = *(const bfrag*)&Bs[(wc + ni * 16 + l15) * BK + rswz];
#pragma unroll
        for (int mi = 0; mi < MI; mi++)
#pragma unroll
            for (int ni = 0; ni < NI; ni++)
                acc[mi][ni] = __builtin_amdgcn_mfma_f32_16x16x32_bf16(
                    af[mi], bf[ni], acc[mi][ni], 0, 0, 0);
    }

    float bv[NI];
    int cols[NI];
#pragma unroll
    for (int ni = 0; ni < NI; ni++) {
        cols[ni] = col0 + wc + ni * 16 + l15;
        if (BSEL == 1) {
            int seg = cols[ni] >> 10;
            const float* bp = (seg == 0) ? bias : (seg == 1) ? bias2 : bias3;
            bv[ni] = bp[cols[ni] & 1023];
        } else {
            bv[ni] = bias[cols[ni]];
        }
    }
#pragma unroll
    for (int mi = 0; mi < MI; mi++) {
        int rbase = row0 + wr + mi * 16 + quad * 4;
#pragma unroll
        for (int r = 0; r < 4; r++) {
            int row = rbase + r;
#pragma unroll
            for (int ni = 0; ni < NI; ni++) {
                float val = acc[mi][ni][r] + bv[ni];
                size_t idx = (size_t)row * N + cols[ni];
                if (EPI == 1) {
                    ((u16*)Cout)[idx] = f2bf(val);
                } else {
                    ((float*)Cout)[idx] = val + res[idx];
                }
            }
        }
    }
}

// ---------------- fused GeGLU FFN GEMM: H = (A@W1+b1) * gelu(A@W2+b2) -------
// A [4096][1024] bf16, W12T [8192][1024] bf16 (W1 cols then W2 cols).
// grid (32, 32): block computes rows ry*128, cols cx*128 of BOTH halves.
__global__ __launch_bounds__(256, 2) void gemm_w12(const u16* __restrict__ A,
                                                   const u16* __restrict__ W12T,
                                                   const float* __restrict__ b1,
                                                   const float* __restrict__ b2,
                                                   u16* __restrict__ H) {
    __shared__ u16 As[128 * BK];
    __shared__ u16 B1s[128 * BK];
    __shared__ u16 B2s[128 * BK];
    int tid = threadIdx.x, wave = tid >> 6, lane = tid & 63;
    int quad = lane >> 4, l15 = lane & 15;
    int row0 = blockIdx.y * 128, col0 = blockIdx.x * 128;
    int wr = (wave >> 1) * 64, wc = (wave & 1) * 64;
    int swz = ((lane & 3) ^ ((lane >> 2) & 3)) * 8;
    int rswz = (quad ^ (l15 & 3)) * 8;

    f32x4 acc1[4][4] = {}, acc2[4][4] = {};

    const u16* gA  = A    + (size_t)(row0 + wave * 32 + (lane >> 2)) * 1024 + swz;
    const u16* gB1 = W12T + (size_t)(col0 + wave * 32 + (lane >> 2)) * 1024 + swz;
    const u16* gB2 = gB1  + (size_t)4096 * 1024;
    u16* lA  = &As [wave * 32 * BK];
    u16* lB1 = &B1s[wave * 32 * BK];
    u16* lB2 = &B2s[wave * 32 * BK];

    for (int k0 = 0; k0 < 1024; k0 += BK) {
        __syncthreads();
        g2l16(gA  + k0,             lA);
        g2l16(gA  + k0 + 16 * 1024, lA  + 16 * BK);
        g2l16(gB1 + k0,             lB1);
        g2l16(gB1 + k0 + 16 * 1024, lB1 + 16 * BK);
        g2l16(gB2 + k0,             lB2);
        g2l16(gB2 + k0 + 16 * 1024, lB2 + 16 * BK);
        __syncthreads();
        bfrag af[4], b1f[4], b2f[4];
#pragma unroll
        for (int mi = 0; mi < 4; mi++)
            af[mi] = *(const bfrag*)&As[(wr + mi * 16 + l15) * BK + rswz];
#pragma unroll
        for (int ni = 0; ni < 4; ni++) {
            b1f[ni] = *(const bfrag*)&B1s[(wc + ni * 16 + l15) * BK + rswz];
            b2f[ni] = *(const bfrag*)&B2s[(wc + ni * 16 + l15) * BK + rswz];
        }
#pragma unroll
        for (int mi = 0; mi < 4; mi++)
#pragma unroll
            for (int ni = 0; ni < 4; ni++) {
                acc1[mi][ni] = __builtin_amdgcn_mfma_f32_16x16x32_bf16(
                    af[mi], b1f[ni], acc1[mi][ni], 0, 0, 0);
                acc2[mi][ni] = __builtin_amdgcn_mfma_f32_16x16x32_bf16(
                    af[mi], b2f[ni], acc2[mi][ni], 0, 0, 0);
            }
    }

    float bv1[4], bv2[4];
    int cols[4];
#pragma unroll
    for (int ni = 0; ni < 4; ni++) {
        cols[ni] = col0 + wc + ni * 16 + l15;
        bv1[ni] = b1[cols[ni]];
        bv2[ni] = b2[cols[ni]];
    }
#pragma unroll
    for (int mi = 0; mi < 4; mi++) {
        int rbase = row0 + wr + mi * 16 + quad * 4;
#pragma unroll
        for (int r = 0; r < 4; r++) {
#pragma unroll
            for (int ni = 0; ni < 4; ni++) {
                float x1 = acc1[mi][ni][r] + bv1[ni];
                float x2 = acc2[mi][ni][r] + bv2[ni];
                H[(size_t)(rbase + r) * 4096 + cols[ni]] = f2bf(x1 * gelu_tanh(x2));
            }
        }
    }
}

// ---------------- split-K GEMM for W3: partials in bf16 ---------------------
// grid (8, 32, 4): kz = blockIdx.z covers K-range [kz*1024, kz*1024+1024).
__global__ __launch_bounds__(256) void gemm_splitk(const u16* __restrict__ A,
                                                   const u16* __restrict__ Bt,
                                                   u16* __restrict__ p0,
                                                   u16* __restrict__ p1,
                                                   u16* __restrict__ p2,
                                                   u16* __restrict__ p3) {
    const int K = 4096, N = 1024;
    __shared__ u16 As[128 * BK];
    __shared__ u16 Bs[128 * BK];
    int tid = threadIdx.x, wave = tid >> 6, lane = tid & 63;
    int quad = lane >> 4, l15 = lane & 15;
    int row0 = blockIdx.y * 128, col0 = blockIdx.x * 128;
    int kz = blockIdx.z;
    u16* P = (kz == 0) ? p0 : (kz == 1) ? p1 : (kz == 2) ? p2 : p3;
    int wr = (wave >> 1) * 64, wc = (wave & 1) * 64;
    int swz = ((lane & 3) ^ ((lane >> 2) & 3)) * 8;
    int rswz = (quad ^ (l15 & 3)) * 8;

    f32x4 acc[4][4] = {};

    const u16* gA = A  + (size_t)(row0 + wave * 32 + (lane >> 2)) * K + kz * 1024 + swz;
    const u16* gB = Bt + (size_t)(col0 + wave * 32 + (lane >> 2)) * K + kz * 1024 + swz;
    u16* lA = &As[wave * 32 * BK];
    u16* lB = &Bs[wave * 32 * BK];

    for (int k0 = 0; k0 < 1024; k0 += BK) {
        __syncthreads();
        g2l16(gA + k0,          lA);
        g2l16(gA + k0 + 16 * K, lA + 16 * BK);
        g2l16(gB + k0,          lB);
        g2l16(gB + k0 + 16 * K, lB + 16 * BK);
        __syncthreads();
        bfrag af[4], bf[4];
#pragma unroll
        for (int mi = 0; mi < 4; mi++)
            af[mi] = *(const bfrag*)&As[(wr + mi * 16 + l15) * BK + rswz];
#pragma unroll
        for (int ni = 0; ni < 4; ni++)
            bf[ni] = *(const bfrag*)&Bs[(wc + ni * 16 + l15) * BK + rswz];
#pragma unroll
        for (int mi = 0; mi < 4; mi++)
#pragma unroll
            for (int ni = 0; ni < 4; ni++)
                acc[mi][ni] = __builtin_amdgcn_mfma_f32_16x16x32_bf16(
                    af[mi], bf[ni], acc[mi][ni], 0, 0, 0);
    }

#pragma unroll
    for (int mi = 0; mi < 4; mi++) {
        int rbase = row0 + wr + mi * 16 + quad * 4;
#pragma unroll
        for (int r = 0; r < 4; r++)
#pragma unroll
            for (int ni = 0; ni < 4; ni++)
                P[(size_t)(rbase + r) * N + wc + col0 + ni * 16 + l15] =
                    f2bf(acc[mi][ni][r]);
    }
}

// ---------------- reduce: out = xmid + b3 + sum of 4 bf16 partials ----------
__global__ __launch_bounds__(256) void reduce4(const u16* __restrict__ p0,
                                               const u16* __restrict__ p1,
                                               const u16* __restrict__ p2,
                                               const u16* __restrict__ p3,
                                               const float* __restrict__ xmid,
                                               const float* __restrict__ b3,
                                               float* __restrict__ out) {
    size_t i = ((size_t)blockIdx.x * 256 + threadIdx.x) * 4;
    float4 xm = *(const float4*)&xmid[i];
    float4 bb = *(const float4*)&b3[i & 1023];
    u16x4 a0 = *(const u16x4*)&p0[i];
    u16x4 a1 = *(const u16x4*)&p1[i];
    u16x4 a2 = *(const u16x4*)&p2[i];
    u16x4 a3 = *(const u16x4*)&p3[i];
    float4 o;
    o.x = xm.x + bb.x + bf2f(a0[0]) + bf2f(a1[0]) + bf2f(a2[0]) + bf2f(a3[0]);
    o.y = xm.y + bb.y + bf2f(a0[1]) + bf2f(a1[1]) + bf2f(a2[1]) + bf2f(a3[1]);
    o.z = xm.z + bb.z + bf2f(a0[2]) + bf2f(a1[2]) + bf2f(a2[2]) + bf2f(a3[2]);
    o.w = xm.w + bb.w + bf2f(a0[3]) + bf2f(a1[3]) + bf2f(a2[3]) + bf2f(a3[3]);
    *(float4*)&out[i] = o;
}

// ---------------- Flash attention on packed qkv [4096][3072] ----------------
#define LP 72
__global__ __launch_bounds__(256) void flash(const u16* __restrict__ qkv,
                                             u16* __restrict__ o) {
    int qt = blockIdx.x, h = blockIdx.y, b = blockIdx.z;
    int tid = threadIdx.x, wave = tid >> 6, lane = tid & 63;
    int quad = lane >> 4, l15 = lane & 15;

    __shared__ u16 Qs[128 * LP];
    __shared__ u16 Ks[64 * LP];
    __shared__ u16 Vt[64 * LP];   // [d][key]
    __shared__ u16 Ps[128 * LP];

    {
        int row = tid >> 1, half = tid & 1;
        const u16* src = qkv + (size_t)(b * 1024 + qt * 128 + row) * 3072 + h * 64 + half * 32;
        u16* dst = &Qs[row * LP + half * 32];
#pragma unroll
        for (int i = 0; i < 4; i++)
            ((u16x8*)dst)[i] = ((const u16x8*)src)[i];
    }

    f32x4 accO[2][4] = {};
    float m_run[2][4], l_run[2][4];
#pragma unroll
    for (int rt = 0; rt < 2; rt++)
#pragma unroll
        for (int r = 0; r < 4; r++) { m_run[rt][r] = -1e30f; l_run[rt][r] = 0.0f; }

    for (int kt = 0; kt < 16; kt++) {
        __syncthreads();
        {
            int row = tid >> 2, seg = tid & 3;
            size_t gb = (size_t)(b * 1024 + kt * 64 + row) * 3072 + h * 64;
            const u16* ksrc = qkv + gb + 1024 + seg * 16;
            *(u16x8*)&Ks[row * LP + seg * 16]     = *(const u16x8*)ksrc;
            *(u16x8*)&Ks[row * LP + seg * 16 + 8] = *(const u16x8*)(ksrc + 8);
            const u16* vsrc = qkv + gb + 2048 + seg * 16;
            u16x8 v0 = *(const u16x8*)vsrc, v1 = *(const u16x8*)(vsrc + 8);
#pragma unroll
            for (int j = 0; j < 8; j++) Vt[(seg * 16 + j) * LP + row]     = v0[j];
#pragma unroll
            for (int j = 0; j < 8; j++) Vt[(seg * 16 + 8 + j) * LP + row] = v1[j];
        }
        __syncthreads();

        f32x4 accS[2][4] = {};
#pragma unroll
        for (int kk = 0; kk < 2; kk++) {
            bfrag aq[2];
#pragma unroll
            for (int rt = 0; rt < 2; rt++)
                aq[rt] = *(const bfrag*)&Qs[(wave * 32 + rt * 16 + l15) * LP + kk * 32 + quad * 8];
#pragma unroll
            for (int ct = 0; ct < 4; ct++) {
                bfrag bk = *(const bfrag*)&Ks[(ct * 16 + l15) * LP + kk * 32 + quad * 8];
                accS[0][ct] = __builtin_amdgcn_mfma_f32_16x16x32_bf16(aq[0], bk, accS[0][ct], 0, 0, 0);
                accS[1][ct] = __builtin_amdgcn_mfma_f32_16x16x32_bf16(aq[1], bk, accS[1][ct], 0, 0, 0);
            }
        }

#pragma unroll
        for (int rt = 0; rt < 2; rt++) {
#pragma unroll
            for (int r = 0; r < 4; r++) {
                float tmax = accS[rt][0][r];
#pragma unroll
                for (int ct = 1; ct < 4; ct++) tmax = fmaxf(tmax, accS[rt][ct][r]);
#pragma unroll
                for (int m = 1; m < 16; m <<= 1) tmax = fmaxf(tmax, __shfl_xor(tmax, m));
                float mnew  = fmaxf(m_run[rt][r], tmax);
                float alpha = __expf(m_run[rt][r] - mnew);
                float lsum = 0.0f;
                float p[4];
#pragma unroll
                for (int ct = 0; ct < 4; ct++) {
                    p[ct] = __expf(accS[rt][ct][r] - mnew);
                    lsum += p[ct];
                }
#pragma unroll
                for (int m = 1; m < 16; m <<= 1) lsum += __shfl_xor(lsum, m);
                l_run[rt][r] = l_run[rt][r] * alpha + lsum;
                m_run[rt][r] = mnew;
#pragma unroll
                for (int oc = 0; oc < 4; oc++) accO[rt][oc][r] *= alpha;
                int prow = wave * 32 + rt * 16 + quad * 4 + r;
#pragma unroll
                for (int ct = 0; ct < 4; ct++)
                    Ps[prow * LP + ct * 16 + l15] = f2bf(p[ct]);
            }
        }

#pragma unroll
        for (int kk = 0; kk < 2; kk++) {
            bfrag ap[2];
#pragma unroll
            for (int rt = 0; rt < 2; rt++)
                ap[rt] = *(const bfrag*)&Ps[(wave * 32 + rt * 16 + l15) * LP + kk * 32 + quad * 8];
#pragma unroll
            for (int oc = 0; oc < 4; oc++) {
                bfrag bv = *(const bfrag*)&Vt[(oc * 16 + l15) * LP + kk * 32 + quad * 8];
                accO[0][oc] = __builtin_amdgcn_mfma_f32_16x16x32_bf16(ap[0], bv, accO[0][oc], 0, 0, 0);
                accO[1][oc] = __builtin_amdgcn_mfma_f32_16x16x32_bf16(ap[1], bv, accO[1][oc], 0, 0, 0);
            }
        }
    }

#pragma unroll
    for (int rt = 0; rt < 2; rt++) {
#pragma unroll
        for (int r = 0; r < 4; r++) {
            int srow = qt * 128 + wave * 32 + rt * 16 + quad * 4 + r;
            float linv = 1.0f / l_run[rt][r];
#pragma unroll
            for (int oc = 0; oc < 4; oc++)
                o[(size_t)(b * 1024 + srow) * 1024 + h * 64 + oc * 16 + l15] =
                    f2bf(accO[rt][oc][r] * linv);
        }
    }
}

// ---------------------------------------------------------------------------
extern "C" void kernel_launch(void* const* d_in, const int* in_sizes, int n_in,
                              void* d_out, int out_size, void* d_ws, size_t ws_size,
                              hipStream_t stream) {
    const float* x     = (const float*)d_in[0];
    const float* ln1_s = (const float*)d_in[2];
    const float* ln1_b = (const float*)d_in[3];
    const float* Wq = (const float*)d_in[4];  const float* bq = (const float*)d_in[5];
    const float* Wk = (const float*)d_in[6];  const float* bk = (const float*)d_in[7];
    const float* Wv = (const float*)d_in[8];  const float* bv = (const float*)d_in[9];
    const float* qn_s = (const float*)d_in[10]; const float* qn_b = (const float*)d_in[11];
    const float* kn_s = (const float*)d_in[12]; const float* kn_b = (const float*)d_in[13];
    const float* Wo = (const float*)d_in[14]; const float* bo = (const float*)d_in[15];
    const float* ln2_s = (const float*)d_in[16]; const float* ln2_b = (const float*)d_in[17];
    const float* W1 = (const float*)d_in[18]; const float* b1 = (const float*)d_in[19];
    const float* W2 = (const float*)d_in[20]; const float* b2 = (const float*)d_in[21];
    const float* W3 = (const float*)d_in[22]; const float* b3 = (const float*)d_in[23];
    float* out = (float*)d_out;

    char* ws = (char*)d_ws;
    const size_t MB = (size_t)1 << 20;
    // lifetimes (MB offsets):
    u16* WqkvT = (u16*)(ws + 0);         // 0..6    dead after QKV; then p0 @0
    u16* WoT   = (u16*)(ws + 6 * MB);    // 6..8    dead after Wo
    u16* W12T  = (u16*)(ws + 8 * MB);    // 8..24   dead after W12; then p1/p2
    u16* W3T   = (u16*)(ws + 24 * MB);   // 24..32  dead after splitk
    u16* xn1   = (u16*)(ws + 32 * MB);   // 32..40  dead after QKV
    u16* attn  = (u16*)(ws + 32 * MB);   //   reuse: dead after Wo
    u16* xn2   = (u16*)(ws + 32 * MB);   //   reuse: dead after W12
    u16* qkv   = (u16*)(ws + 40 * MB);   // 40..64  dead after flash
    float* xmid = (float*)(ws + 40 * MB);//   reuse: 40..56, alive until reduce
    u16* p3    = (u16*)(ws + 56 * MB);   // 56..64
    u16* h     = (u16*)(ws + 64 * MB);   // 64..96  dead after splitk
    u16* p0    = (u16*)(ws + 0);
    u16* p1    = (u16*)(ws + 8 * MB);
    u16* p2    = (u16*)(ws + 16 * MB);
    // peak = 96 MB

    dim3 blk(256);

    wt_all<<<16384, blk, 0, stream>>>(Wq, Wk, Wv, Wo, W1, W2, W3,
                                      WqkvT, WoT, W12T, W3T);

    ln1024<<<4096, blk, 0, stream>>>(x, ln1_s, ln1_b, xn1);

    // fused QKV: [4096,1024] @ [3072,1024]^T -> qkv
    gemm_bt<1, 128, 1><<<dim3(24, 32), blk, 0, stream>>>(
        xn1, WqkvT, bq, bk, bv, nullptr, qkv, 4096, 3072, 1024);

    qknorm2<<<32768, blk, 0, stream>>>(qkv, qn_s, qn_b, kn_s, kn_b);

    flash<<<dim3(8, 16, 4), blk, 0, stream>>>(qkv, attn);

    // xmid = x + attn @ Wo + bo
    gemm_bt<2, 64, 0><<<dim3(16, 32), blk, 0, stream>>>(
        attn, WoT, bo, nullptr, nullptr, x, xmid, 4096, 1024, 1024);

    ln1024<<<4096, blk, 0, stream>>>(xmid, ln2_s, ln2_b, xn2);

    // fused GeGLU FFN: h = (xn2@W1+b1) * gelu(xn2@W2+b2)
    gemm_w12<<<dim3(32, 32), blk, 0, stream>>>(xn2, W12T, b1, b2, h);

    // W3 split-K=4: partials
    gemm_splitk<<<dim3(8, 32, 4), blk, 0, stream>>>(h, W3T, p0, p1, p2, p3);

    // out = xmid + b3 + sum(partials)
    reduce4<<<4096, blk, 0, stream>>>(p0, p1, p2, p3, xmid, b3, out);
}

// Round 4
// 452.175 us; speedup vs baseline: 1.3908x; 1.0411x over previous
//
#include <hip/hip_runtime.h>

typedef unsigned short u16;
typedef __bf16  bfrag  __attribute__((ext_vector_type(8)));   // MFMA A/B operand (4 VGPRs)
typedef float   f32x4  __attribute__((ext_vector_type(4)));   // MFMA C/D operand
typedef u16     u16x8  __attribute__((ext_vector_type(8)));
typedef u16     u16x4  __attribute__((ext_vector_type(4)));

__device__ __forceinline__ float bf2f(u16 u) {
    unsigned v = ((unsigned)u) << 16;
    return __builtin_bit_cast(float, v);
}
__device__ __forceinline__ u16 f2bf(float f) {   // round-to-nearest-even
    unsigned x = __builtin_bit_cast(unsigned, f);
    unsigned r = (x + 0x7fffu + ((x >> 16) & 1u)) >> 16;
    return (u16)r;
}
__device__ __forceinline__ void g2l16(const u16* g, u16* l) {
    // 16B per lane -> lds_base + lane*16 (wave-uniform LDS base)
    __builtin_amdgcn_global_load_lds((__attribute__((address_space(1))) void*)g,
                                     (__attribute__((address_space(3))) void*)l, 16, 0, 0);
}
__device__ __forceinline__ float gelu_tanh(float x) {
    // 0.5x(1+tanh(c)) == x * sigmoid(2c)
    float c = 1.5957691216057308f * (x + 0.044715f * x * x * x);
    return x * __frcp_rn(1.0f + __expf(-c));
}

// Period-8 LDS swizzle (bank-conflict-free fragment reads):
//   phys_seg = seg ^ ((row>>1)&3), seg = 16B chunk within the 64B k-row.
// Staging source k-offset for lane (row = lane>>2, seg = lane&3):
#define SWZ(lane)  ((((lane) & 3) ^ (((lane) >> 3) & 3)) * 8)
// Fragment-read k-offset (row ≡ l15 mod 16, bases ≡0 mod 16):
#define RSWZ(quad, l15)  ((((quad) ^ (((l15) >> 1) & 3))) * 8)

// ---------------- all 7 weight transposes in ONE kernel ---------------------
// Wt[c][r] = bf16(W[r][c]). W1/W2 pack into W12T [8192][1024].
__global__ __launch_bounds__(256) void wt_all(
        const float* __restrict__ Wq, const float* __restrict__ Wk,
        const float* __restrict__ Wv, const float* __restrict__ Wo,
        const float* __restrict__ W1, const float* __restrict__ W2,
        const float* __restrict__ W3,
        u16* __restrict__ WqkvT, u16* __restrict__ WoT,
        u16* __restrict__ W12T, u16* __restrict__ W3T) {
    int blk = blockIdx.x;
    const float* W; u16* Wt; int R, C, local;
    if (blk < 3072) {          // Wq/Wk/Wv -> packed WqkvT [3072][1024]
        int w = blk >> 10; local = blk & 1023;
        W = (w == 0) ? Wq : (w == 1) ? Wk : Wv;
        Wt = WqkvT + (size_t)w * 1024 * 1024; R = 1024; C = 1024;
    } else if (blk < 4096) { W = Wo; Wt = WoT; R = 1024; C = 1024; local = blk - 3072; }
    else if (blk < 8192)   { W = W1; Wt = W12T; R = 1024; C = 4096; local = blk - 4096; }
    else if (blk < 12288)  { W = W2; Wt = W12T + (size_t)4096 * 1024; R = 1024; C = 4096; local = blk - 8192; }
    else                   { W = W3; Wt = W3T; R = 4096; C = 1024; local = blk - 12288; }
    int tiles_x = C >> 5;
    int c0 = (local % tiles_x) * 32, r0 = (local / tiles_x) * 32;

    __shared__ float tile[32][33];
    int tx = threadIdx.x & 31, ty = threadIdx.x >> 5;   // ty in [0,8)
#pragma unroll
    for (int i = 0; i < 32; i += 8)
        tile[ty + i][tx] = W[(size_t)(r0 + ty + i) * C + c0 + tx];
    __syncthreads();
#pragma unroll
    for (int i = 0; i < 32; i += 8)
        Wt[(size_t)(c0 + ty + i) * R + r0 + tx] = f2bf(tile[tx][ty + i]);
}

// ---------------- LayerNorm over D=1024, fp32 in -> bf16 out ----------------
__global__ __launch_bounds__(256) void ln1024(const float* __restrict__ x,
                                              const float* __restrict__ s,
                                              const float* __restrict__ bi,
                                              u16* __restrict__ out) {
    int row = blockIdx.x, t = threadIdx.x;
    const float4* xr = (const float4*)(x + (size_t)row * 1024);
    float4 v = xr[t];
    float sum = v.x + v.y + v.z + v.w;
    float sq  = v.x * v.x + v.y * v.y + v.z * v.z + v.w * v.w;
#pragma unroll
    for (int off = 1; off < 64; off <<= 1) {
        sum += __shfl_xor(sum, off);
        sq  += __shfl_xor(sq,  off);
    }
    __shared__ float s1[4], s2[4];
    int wave = t >> 6;
    if ((t & 63) == 0) { s1[wave] = sum; s2[wave] = sq; }
    __syncthreads();
    sum = s1[0] + s1[1] + s1[2] + s1[3];
    sq  = s2[0] + s2[1] + s2[2] + s2[3];
    float mean = sum * (1.0f / 1024.0f);
    float var  = sq  * (1.0f / 1024.0f) - mean * mean;
    float inv  = rsqrtf(var + 1e-6f);
    float4 sc = ((const float4*)s)[t], bb = ((const float4*)bi)[t];
    u16x4 o;
    o[0] = f2bf((v.x - mean) * inv * sc.x + bb.x);
    o[1] = f2bf((v.y - mean) * inv * sc.y + bb.y);
    o[2] = f2bf((v.z - mean) * inv * sc.z + bb.z);
    o[3] = f2bf((v.w - mean) * inv * sc.w + bb.w);
    *(u16x4*)&out[(size_t)row * 1024 + t * 4] = o;
}

// ---------------- GEMM: C[M,N] = A[M,K] @ Bt[N,K]^T, bf16 MFMA, fp32 acc ----
// EPI 1: bf16=acc+bias | 2: fp32=acc+bias+res
// EPI 4: QKV epilogue — per-head LayerNorm over the 64-col head dim on the
//        fp32 accumulator (wave's 64 cols == one head), q scaled by 0.125.
// BSEL 1: bias is 3 packed 1024-wide segments
#define BM 128
#define BK 32
template <int EPI, int BN_, int BSEL>
__global__ __launch_bounds__(256) void gemm_bt(const u16* __restrict__ A,
                                               const u16* __restrict__ Bt,
                                               const float* __restrict__ bias,
                                               const float* __restrict__ bias2,
                                               const float* __restrict__ bias3,
                                               const float* __restrict__ res,
                                               const float* __restrict__ qn_s,
                                               const float* __restrict__ qn_b,
                                               const float* __restrict__ kn_s,
                                               const float* __restrict__ kn_b,
                                               void* __restrict__ Cout,
                                               int M, int N, int K) {
    __shared__ u16 As[BM * BK];
    __shared__ u16 Bs[BN_ * BK];
    constexpr int MI = (BN_ == 128) ? 4 : 2;
    constexpr int NI = 4;
    int tid = threadIdx.x, wave = tid >> 6, lane = tid & 63;
    int quad = lane >> 4, l15 = lane & 15;
    int row0 = blockIdx.y * BM, col0 = blockIdx.x * BN_;
    int wr = (BN_ == 128) ? (wave >> 1) * 64 : wave * 32;
    int wc = (BN_ == 128) ? (wave & 1) * 64 : 0;
    int swz = SWZ(lane);
    int rswz = RSWZ(quad, l15);

    f32x4 acc[MI][NI] = {};

    const u16* gA = A + (size_t)(row0 + wave * 32 + (lane >> 2)) * K + swz;
    u16* lA = &As[wave * 32 * BK];
    const u16* gB;
    u16* lB;
    if (BN_ == 128) { gB = Bt + (size_t)(col0 + wave * 32 + (lane >> 2)) * K + swz; lB = &Bs[wave * 32 * BK]; }
    else            { gB = Bt + (size_t)(col0 + wave * 16 + (lane >> 2)) * K + swz; lB = &Bs[wave * 16 * BK]; }

    for (int k0 = 0; k0 < K; k0 += BK) {
        __syncthreads();
        g2l16(gA + k0,          lA);
        g2l16(gA + k0 + 16 * K, lA + 16 * BK);
        if (BN_ == 128) {
            g2l16(gB + k0,          lB);
            g2l16(gB + k0 + 16 * K, lB + 16 * BK);
        } else {
            g2l16(gB + k0, lB);
        }
        __syncthreads();
        bfrag af[MI], bf[NI];
#pragma unroll
        for (int mi = 0; mi < MI; mi++)
            af[mi] = *(const bfrag*)&As[(wr + mi * 16 + l15) * BK + rswz];
#pragma unroll
        for (int ni = 0; ni < NI; ni++)
            bf[ni] = *(const bfrag*)&Bs[(wc + ni * 16 + l15) * BK + rswz];
#pragma unroll
        for (int mi = 0; mi < MI; mi++)
#pragma unroll
            for (int ni = 0; ni < NI; ni++)
                acc[mi][ni] = __builtin_amdgcn_mfma_f32_16x16x32_bf16(
                    af[mi], bf[ni], acc[mi][ni], 0, 0, 0);
    }

    float bv[NI];
    int cols[NI];
#pragma unroll
    for (int ni = 0; ni < NI; ni++) {
        cols[ni] = col0 + wc + ni * 16 + l15;
        if (BSEL == 1) {
            int seg = cols[ni] >> 10;
            const float* bp = (seg == 0) ? bias : (seg == 1) ? bias2 : bias3;
            bv[ni] = bp[cols[ni] & 1023];
        } else {
            bv[ni] = bias[cols[ni]];
        }
    }

    if (EPI == 4) {
        // wave-uniform head info: this wave's 64 cols are one head of q/k/v
        int cbase = col0 + wc;
        int z = cbase >> 10;              // 0=q, 1=k, 2=v
        int hd = (cbase >> 6) & 15;
        float post = (z == 0) ? 0.125f : 1.0f;
        float sn[NI], bn[NI];
        if (z < 2) {
            const float* ns = (z == 0) ? qn_s : kn_s;
            const float* nb = (z == 0) ? qn_b : kn_b;
#pragma unroll
            for (int ni = 0; ni < NI; ni++) {
                sn[ni] = ns[hd * 64 + ni * 16 + l15];
                bn[ni] = nb[hd * 64 + ni * 16 + l15];
            }
        }
#pragma unroll
        for (int mi = 0; mi < MI; mi++) {
            int rbase = row0 + wr + mi * 16 + quad * 4;
#pragma unroll
            for (int r = 0; r < 4; r++) {
                float v0 = acc[mi][0][r] + bv[0];
                float v1 = acc[mi][1][r] + bv[1];
                float v2 = acc[mi][2][r] + bv[2];
                float v3 = acc[mi][3][r] + bv[3];
                size_t rb = (size_t)(rbase + r) * N + cbase;
                if (z == 2) {
                    ((u16*)Cout)[rb + 0 * 16 + l15] = f2bf(v0);
                    ((u16*)Cout)[rb + 1 * 16 + l15] = f2bf(v1);
                    ((u16*)Cout)[rb + 2 * 16 + l15] = f2bf(v2);
                    ((u16*)Cout)[rb + 3 * 16 + l15] = f2bf(v3);
                } else {
                    float s  = v0 + v1 + v2 + v3;
                    float sq = v0 * v0 + v1 * v1 + v2 * v2 + v3 * v3;
#pragma unroll
                    for (int m = 1; m < 16; m <<= 1) {
                        s  += __shfl_xor(s,  m);
                        sq += __shfl_xor(sq, m);
                    }
                    float mean = s * (1.0f / 64.0f);
                    float var  = sq * (1.0f / 64.0f) - mean * mean;
                    float inv  = rsqrtf(var + 1e-6f);
                    ((u16*)Cout)[rb + 0 * 16 + l15] = f2bf(((v0 - mean) * inv * sn[0] + bn[0]) * post);
                    ((u16*)Cout)[rb + 1 * 16 + l15] = f2bf(((v1 - mean) * inv * sn[1] + bn[1]) * post);
                    ((u16*)Cout)[rb + 2 * 16 + l15] = f2bf(((v2 - mean) * inv * sn[2] + bn[2]) * post);
                    ((u16*)Cout)[rb + 3 * 16 + l15] = f2bf(((v3 - mean) * inv * sn[3] + bn[3]) * post);
                }
            }
        }
        return;
    }

#pragma unroll
    for (int mi = 0; mi < MI; mi++) {
        int rbase = row0 + wr + mi * 16 + quad * 4;
#pragma unroll
        for (int r = 0; r < 4; r++) {
            int row = rbase + r;
#pragma unroll
            for (int ni = 0; ni < NI; ni++) {
                float val = acc[mi][ni][r] + bv[ni];
                size_t idx = (size_t)row * N + cols[ni];
                if (EPI == 1) {
                    ((u16*)Cout)[idx] = f2bf(val);
                } else {
                    ((float*)Cout)[idx] = val + res[idx];
                }
            }
        }
    }
}

// ---------------- fused GeGLU FFN GEMM: H = (A@W1+b1) * gelu(A@W2+b2) -------
__global__ __launch_bounds__(256, 2) void gemm_w12(const u16* __restrict__ A,
                                                   const u16* __restrict__ W12T,
                                                   const float* __restrict__ b1,
                                                   const float* __restrict__ b2,
                                                   u16* __restrict__ H) {
    __shared__ u16 As[128 * BK];
    __shared__ u16 B1s[128 * BK];
    __shared__ u16 B2s[128 * BK];
    int tid = threadIdx.x, wave = tid >> 6, lane = tid & 63;
    int quad = lane >> 4, l15 = lane & 15;
    int row0 = blockIdx.y * 128, col0 = blockIdx.x * 128;
    int wr = (wave >> 1) * 64, wc = (wave & 1) * 64;
    int swz = SWZ(lane);
    int rswz = RSWZ(quad, l15);

    f32x4 acc1[4][4] = {}, acc2[4][4] = {};

    const u16* gA  = A    + (size_t)(row0 + wave * 32 + (lane >> 2)) * 1024 + swz;
    const u16* gB1 = W12T + (size_t)(col0 + wave * 32 + (lane >> 2)) * 1024 + swz;
    const u16* gB2 = gB1  + (size_t)4096 * 1024;
    u16* lA  = &As [wave * 32 * BK];
    u16* lB1 = &B1s[wave * 32 * BK];
    u16* lB2 = &B2s[wave * 32 * BK];

    for (int k0 = 0; k0 < 1024; k0 += BK) {
        __syncthreads();
        g2l16(gA  + k0,             lA);
        g2l16(gA  + k0 + 16 * 1024, lA  + 16 * BK);
        g2l16(gB1 + k0,             lB1);
        g2l16(gB1 + k0 + 16 * 1024, lB1 + 16 * BK);
        g2l16(gB2 + k0,             lB2);
        g2l16(gB2 + k0 + 16 * 1024, lB2 + 16 * BK);
        __syncthreads();
        bfrag af[4], b1f[4], b2f[4];
#pragma unroll
        for (int mi = 0; mi < 4; mi++)
            af[mi] = *(const bfrag*)&As[(wr + mi * 16 + l15) * BK + rswz];
#pragma unroll
        for (int ni = 0; ni < 4; ni++) {
            b1f[ni] = *(const bfrag*)&B1s[(wc + ni * 16 + l15) * BK + rswz];
            b2f[ni] = *(const bfrag*)&B2s[(wc + ni * 16 + l15) * BK + rswz];
        }
#pragma unroll
        for (int mi = 0; mi < 4; mi++)
#pragma unroll
            for (int ni = 0; ni < 4; ni++) {
                acc1[mi][ni] = __builtin_amdgcn_mfma_f32_16x16x32_bf16(
                    af[mi], b1f[ni], acc1[mi][ni], 0, 0, 0);
                acc2[mi][ni] = __builtin_amdgcn_mfma_f32_16x16x32_bf16(
                    af[mi], b2f[ni], acc2[mi][ni], 0, 0, 0);
            }
    }

    float bv1[4], bv2[4];
    int cols[4];
#pragma unroll
    for (int ni = 0; ni < 4; ni++) {
        cols[ni] = col0 + wc + ni * 16 + l15;
        bv1[ni] = b1[cols[ni]];
        bv2[ni] = b2[cols[ni]];
    }
#pragma unroll
    for (int mi = 0; mi < 4; mi++) {
        int rbase = row0 + wr + mi * 16 + quad * 4;
#pragma unroll
        for (int r = 0; r < 4; r++) {
#pragma unroll
            for (int ni = 0; ni < 4; ni++) {
                float x1 = acc1[mi][ni][r] + bv1[ni];
                float x2 = acc2[mi][ni][r] + bv2[ni];
                H[(size_t)(rbase + r) * 4096 + cols[ni]] = f2bf(x1 * gelu_tanh(x2));
            }
        }
    }
}

// ---------------- split-K GEMM for W3: partials in bf16 ---------------------
__global__ __launch_bounds__(256) void gemm_splitk(const u16* __restrict__ A,
                                                   const u16* __restrict__ Bt,
                                                   u16* __restrict__ p0,
                                                   u16* __restrict__ p1,
                                                   u16* __restrict__ p2,
                                                   u16* __restrict__ p3) {
    const int K = 4096, N = 1024;
    __shared__ u16 As[128 * BK];
    __shared__ u16 Bs[128 * BK];
    int tid = threadIdx.x, wave = tid >> 6, lane = tid & 63;
    int quad = lane >> 4, l15 = lane & 15;
    int row0 = blockIdx.y * 128, col0 = blockIdx.x * 128;
    int kz = blockIdx.z;
    u16* P = (kz == 0) ? p0 : (kz == 1) ? p1 : (kz == 2) ? p2 : p3;
    int wr = (wave >> 1) * 64, wc = (wave & 1) * 64;
    int swz = SWZ(lane);
    int rswz = RSWZ(quad, l15);

    f32x4 acc[4][4] = {};

    const u16* gA = A  + (size_t)(row0 + wave * 32 + (lane >> 2)) * K + kz * 1024 + swz;
    const u16* gB = Bt + (size_t)(col0 + wave * 32 + (lane >> 2)) * K + kz * 1024 + swz;
    u16* lA = &As[wave * 32 * BK];
    u16* lB = &Bs[wave * 32 * BK];

    for (int k0 = 0; k0 < 1024; k0 += BK) {
        __syncthreads();
        g2l16(gA + k0,          lA);
        g2l16(gA + k0 + 16 * K, lA + 16 * BK);
        g2l16(gB + k0,          lB);
        g2l16(gB + k0 + 16 * K, lB + 16 * BK);
        __syncthreads();
        bfrag af[4], bf[4];
#pragma unroll
        for (int mi = 0; mi < 4; mi++)
            af[mi] = *(const bfrag*)&As[(wr + mi * 16 + l15) * BK + rswz];
#pragma unroll
        for (int ni = 0; ni < 4; ni++)
            bf[ni] = *(const bfrag*)&Bs[(wc + ni * 16 + l15) * BK + rswz];
#pragma unroll
        for (int mi = 0; mi < 4; mi++)
#pragma unroll
            for (int ni = 0; ni < 4; ni++)
                acc[mi][ni] = __builtin_amdgcn_mfma_f32_16x16x32_bf16(
                    af[mi], bf[ni], acc[mi][ni], 0, 0, 0);
    }

#pragma unroll
    for (int mi = 0; mi < 4; mi++) {
        int rbase = row0 + wr + mi * 16 + quad * 4;
#pragma unroll
        for (int r = 0; r < 4; r++)
#pragma unroll
            for (int ni = 0; ni < 4; ni++)
                P[(size_t)(rbase + r) * N + wc + col0 + ni * 16 + l15] =
                    f2bf(acc[mi][ni][r]);
    }
}

// ---------------- reduce: out = xmid + b3 + sum of 4 bf16 partials ----------
__global__ __launch_bounds__(256) void reduce4(const u16* __restrict__ p0,
                                               const u16* __restrict__ p1,
                                               const u16* __restrict__ p2,
                                               const u16* __restrict__ p3,
                                               const float* __restrict__ xmid,
                                               const float* __restrict__ b3,
                                               float* __restrict__ out) {
    size_t i = ((size_t)blockIdx.x * 256 + threadIdx.x) * 4;
    float4 xm = *(const float4*)&xmid[i];
    float4 bb = *(const float4*)&b3[i & 1023];
    u16x4 a0 = *(const u16x4*)&p0[i];
    u16x4 a1 = *(const u16x4*)&p1[i];
    u16x4 a2 = *(const u16x4*)&p2[i];
    u16x4 a3 = *(const u16x4*)&p3[i];
    float4 o;
    o.x = xm.x + bb.x + bf2f(a0[0]) + bf2f(a1[0]) + bf2f(a2[0]) + bf2f(a3[0]);
    o.y = xm.y + bb.y + bf2f(a0[1]) + bf2f(a1[1]) + bf2f(a2[1]) + bf2f(a3[1]);
    o.z = xm.z + bb.z + bf2f(a0[2]) + bf2f(a1[2]) + bf2f(a2[2]) + bf2f(a3[2]);
    o.w = xm.w + bb.w + bf2f(a0[3]) + bf2f(a1[3]) + bf2f(a2[3]) + bf2f(a3[3]);
    *(float4*)&out[i] = o;
}

// ---------------- Flash attention on packed qkv [4096][3072] ----------------
#define LP 72
__global__ __launch_bounds__(256) void flash(const u16* __restrict__ qkv,
                                             u16* __restrict__ o) {
    int qt = blockIdx.x, h = blockIdx.y, b = blockIdx.z;
    int tid = threadIdx.x, wave = tid >> 6, lane = tid & 63;
    int quad = lane >> 4, l15 = lane & 15;

    __shared__ u16 Qs[128 * LP];
    __shared__ u16 Ks[64 * LP];
    __shared__ u16 Vt[64 * LP];   // [d][key]
    __shared__ u16 Ps[128 * LP];

    {
        int row = tid >> 1, half = tid & 1;
        const u16* src = qkv + (size_t)(b * 1024 + qt * 128 + row) * 3072 + h * 64 + half * 32;
        u16* dst = &Qs[row * LP + half * 32];
#pragma unroll
        for (int i = 0; i < 4; i++)
            ((u16x8*)dst)[i] = ((const u16x8*)src)[i];
    }

    f32x4 accO[2][4] = {};
    float m_run[2][4], l_run[2][4];
#pragma unroll
    for (int rt = 0; rt < 2; rt++)
#pragma unroll
        for (int r = 0; r < 4; r++) { m_run[rt][r] = -1e30f; l_run[rt][r] = 0.0f; }

    for (int kt = 0; kt < 16; kt++) {
        __syncthreads();
        {
            int row = tid >> 2, seg = tid & 3;
            size_t gb = (size_t)(b * 1024 + kt * 64 + row) * 3072 + h * 64;
            const u16* ksrc = qkv + gb + 1024 + seg * 16;
            *(u16x8*)&Ks[row * LP + seg * 16]     = *(const u16x8*)ksrc;
            *(u16x8*)&Ks[row * LP + seg * 16 + 8] = *(const u16x8*)(ksrc + 8);
            const u16* vsrc = qkv + gb + 2048 + seg * 16;
            u16x8 v0 = *(const u16x8*)vsrc, v1 = *(const u16x8*)(vsrc + 8);
#pragma unroll
            for (int j = 0; j < 8; j++) Vt[(seg * 16 + j) * LP + row]     = v0[j];
#pragma unroll
            for (int j = 0; j < 8; j++) Vt[(seg * 16 + 8 + j) * LP + row] = v1[j];
        }
        __syncthreads();

        f32x4 accS[2][4] = {};
#pragma unroll
        for (int kk = 0; kk < 2; kk++) {
            bfrag aq[2];
#pragma unroll
            for (int rt = 0; rt < 2; rt++)
                aq[rt] = *(const bfrag*)&Qs[(wave * 32 + rt * 16 + l15) * LP + kk * 32 + quad * 8];
#pragma unroll
            for (int ct = 0; ct < 4; ct++) {
                bfrag bk = *(const bfrag*)&Ks[(ct * 16 + l15) * LP + kk * 32 + quad * 8];
                accS[0][ct] = __builtin_amdgcn_mfma_f32_16x16x32_bf16(aq[0], bk, accS[0][ct], 0, 0, 0);
                accS[1][ct] = __builtin_amdgcn_mfma_f32_16x16x32_bf16(aq[1], bk, accS[1][ct], 0, 0, 0);
            }
        }

#pragma unroll
        for (int rt = 0; rt < 2; rt++) {
#pragma unroll
            for (int r = 0; r < 4; r++) {
                float tmax = accS[rt][0][r];
#pragma unroll
                for (int ct = 1; ct < 4; ct++) tmax = fmaxf(tmax, accS[rt][ct][r]);
#pragma unroll
                for (int m = 1; m < 16; m <<= 1) tmax = fmaxf(tmax, __shfl_xor(tmax, m));
                float mnew  = fmaxf(m_run[rt][r], tmax);
                float alpha = __expf(m_run[rt][r] - mnew);
                float lsum = 0.0f;
                float p[4];
#pragma unroll
                for (int ct = 0; ct < 4; ct++) {
                    p[ct] = __expf(accS[rt][ct][r] - mnew);
                    lsum += p[ct];
                }
#pragma unroll
                for (int m = 1; m < 16; m <<= 1) lsum += __shfl_xor(lsum, m);
                l_run[rt][r] = l_run[rt][r] * alpha + lsum;
                m_run[rt][r] = mnew;
#pragma unroll
                for (int oc = 0; oc < 4; oc++) accO[rt][oc][r] *= alpha;
                int prow = wave * 32 + rt * 16 + quad * 4 + r;
#pragma unroll
                for (int ct = 0; ct < 4; ct++)
                    Ps[prow * LP + ct * 16 + l15] = f2bf(p[ct]);
            }
        }

#pragma unroll
        for (int kk = 0; kk < 2; kk++) {
            bfrag ap[2];
#pragma unroll
            for (int rt = 0; rt < 2; rt++)
                ap[rt] = *(const bfrag*)&Ps[(wave * 32 + rt * 16 + l15) * LP + kk * 32 + quad * 8];
#pragma unroll
            for (int oc = 0; oc < 4; oc++) {
                bfrag bv = *(const bfrag*)&Vt[(oc * 16 + l15) * LP + kk * 32 + quad * 8];
                accO[0][oc] = __builtin_amdgcn_mfma_f32_16x16x32_bf16(ap[0], bv, accO[0][oc], 0, 0, 0);
                accO[1][oc] = __builtin_amdgcn_mfma_f32_16x16x32_bf16(ap[1], bv, accO[1][oc], 0, 0, 0);
            }
        }
    }

#pragma unroll
    for (int rt = 0; rt < 2; rt++) {
#pragma unroll
        for (int r = 0; r < 4; r++) {
            int srow = qt * 128 + wave * 32 + rt * 16 + quad * 4 + r;
            float linv = 1.0f / l_run[rt][r];
#pragma unroll
            for (int oc = 0; oc < 4; oc++)
                o[(size_t)(b * 1024 + srow) * 1024 + h * 64 + oc * 16 + l15] =
                    f2bf(accO[rt][oc][r] * linv);
        }
    }
}

// ---------------------------------------------------------------------------
extern "C" void kernel_launch(void* const* d_in, const int* in_sizes, int n_in,
                              void* d_out, int out_size, void* d_ws, size_t ws_size,
                              hipStream_t stream) {
    const float* x     = (const float*)d_in[0];
    const float* ln1_s = (const float*)d_in[2];
    const float* ln1_b = (const float*)d_in[3];
    const float* Wq = (const float*)d_in[4];  const float* bq = (const float*)d_in[5];
    const float* Wk = (const float*)d_in[6];  const float* bk = (const float*)d_in[7];
    const float* Wv = (const float*)d_in[8];  const float* bv = (const float*)d_in[9];
    const float* qn_s = (const float*)d_in[10]; const float* qn_b = (const float*)d_in[11];
    const float* kn_s = (const float*)d_in[12]; const float* kn_b = (const float*)d_in[13];
    const float* Wo = (const float*)d_in[14]; const float* bo = (const float*)d_in[15];
    const float* ln2_s = (const float*)d_in[16]; const float* ln2_b = (const float*)d_in[17];
    const float* W1 = (const float*)d_in[18]; const float* b1 = (const float*)d_in[19];
    const float* W2 = (const float*)d_in[20]; const float* b2 = (const float*)d_in[21];
    const float* W3 = (const float*)d_in[22]; const float* b3 = (const float*)d_in[23];
    float* out = (float*)d_out;

    char* ws = (char*)d_ws;
    const size_t MB = (size_t)1 << 20;
    u16* WqkvT = (u16*)(ws + 0);         // 0..6    dead after QKV; then p0 @0
    u16* WoT   = (u16*)(ws + 6 * MB);    // 6..8    dead after Wo
    u16* W12T  = (u16*)(ws + 8 * MB);    // 8..24   dead after W12; then p1/p2
    u16* W3T   = (u16*)(ws + 24 * MB);   // 24..32  dead after splitk
    u16* xn1   = (u16*)(ws + 32 * MB);   // 32..40  dead after QKV
    u16* attn  = (u16*)(ws + 32 * MB);   //   reuse: dead after Wo
    u16* xn2   = (u16*)(ws + 32 * MB);   //   reuse: dead after W12
    u16* qkv   = (u16*)(ws + 40 * MB);   // 40..64  dead after flash
    float* xmid = (float*)(ws + 40 * MB);//   reuse: 40..56, alive until reduce
    u16* p3    = (u16*)(ws + 56 * MB);   // 56..64
    u16* h     = (u16*)(ws + 64 * MB);   // 64..96  dead after splitk
    u16* p0    = (u16*)(ws + 0);
    u16* p1    = (u16*)(ws + 8 * MB);
    u16* p2    = (u16*)(ws + 16 * MB);
    // peak = 96 MB

    dim3 blk(256);

    wt_all<<<16384, blk, 0, stream>>>(Wq, Wk, Wv, Wo, W1, W2, W3,
                                      WqkvT, WoT, W12T, W3T);

    ln1024<<<4096, blk, 0, stream>>>(x, ln1_s, ln1_b, xn1);

    // fused QKV + per-head QK-norm in epilogue -> qkv
    gemm_bt<4, 128, 1><<<dim3(24, 32), blk, 0, stream>>>(
        xn1, WqkvT, bq, bk, bv, nullptr, qn_s, qn_b, kn_s, kn_b,
        qkv, 4096, 3072, 1024);

    flash<<<dim3(8, 16, 4), blk, 0, stream>>>(qkv, attn);

    // xmid = x + attn @ Wo + bo
    gemm_bt<2, 64, 0><<<dim3(16, 32), blk, 0, stream>>>(
        attn, WoT, bo, nullptr, nullptr, x, nullptr, nullptr, nullptr, nullptr,
        xmid, 4096, 1024, 1024);

    ln1024<<<4096, blk, 0, stream>>>(xmid, ln2_s, ln2_b, xn2);

    // fused GeGLU FFN: h = (xn2@W1+b1) * gelu(xn2@W2+b2)
    gemm_w12<<<dim3(32, 32), blk, 0, stream>>>(xn2, W12T, b1, b2, h);

    // W3 split-K=4: partials
    gemm_splitk<<<dim3(8, 32, 4), blk, 0, stream>>>(h, W3T, p0, p1, p2, p3);

    // out = xmid + b3 + sum(partials)
    reduce4<<<4096, blk, 0, stream>>>(p0, p1, p2, p3, xmid, b3, out);
}